// Round 4
// baseline (218.323 us; speedup 1.0000x reference)
//
#include <hip/hip_runtime.h>
#include <hip/hip_bf16.h>

typedef unsigned short ushort_t;
typedef __attribute__((ext_vector_type(8))) short s8v;   // 8 bf16 = 4 VGPR (MFMA A/B frag)
typedef __attribute__((ext_vector_type(4))) float f4;    // 4 fp32 acc (MFMA C/D frag)
typedef __attribute__((ext_vector_type(4))) unsigned short u16x4;

// Problem constants: B=2, T=2048, M=512, C=512, H=8, D=64
#define BB 2
#define TT 2048
#define MMM 512
#define CC 512
#define HH 8
#define DD 64
#define SCALE 0.125f
// SCALE * log2(e): folded into q_x so softmax uses bare v_exp_f32 (2^x)
#define SCALE_L2E 0.18033688011112042f

__device__ __forceinline__ ushort_t f2bf(float v) {
    __hip_bfloat16 h = __float2bfloat16(v);
    return *reinterpret_cast<ushort_t*>(&h);
}
__device__ __forceinline__ float bf2f(ushort_t u) {
    __hip_bfloat16 h;
    *reinterpret_cast<ushort_t*>(&h) = u;
    return __bfloat162float(h);
}
// bare 2^x (v_exp_f32). Inputs pre-scaled by log2(e).
__device__ __forceinline__ float exp2_raw(float v) {
    float p;
    asm("v_exp_f32 %0, %1" : "=v"(p) : "v"(v));
    return p;
}

// async global->LDS, 16B per lane. LDS dst = wave-uniform base + lane*16.
__device__ __forceinline__ void gload16(const void* g, void* l) {
    __builtin_amdgcn_global_load_lds((const __attribute__((address_space(1))) void*)g,
                                     (__attribute__((address_space(3))) void*)l, 16, 0, 0);
}

// ---------------------------------------------------------------------------
// prep_k: x/y fp32->bf16 (float4-vectorized) + 5 weight transposes.
// ---------------------------------------------------------------------------
__device__ __forceinline__ void transp32(const float* W, ushort_t* WT, int K, int N,
                                         int bx, int by, int tid) {
    const int k0 = by * 32, n0 = bx * 32;
    __shared__ float t[32][33];
    for (int i = tid; i < 1024; i += 256) {
        int r = i >> 5, c = i & 31;
        t[r][c] = W[(long)(k0 + r) * N + n0 + c];
    }
    __syncthreads();
    for (int i = tid; i < 1024; i += 256) {
        int r = i >> 5, c = i & 31;
        WT[(long)(n0 + r) * K + k0 + c] = f2bf(t[c][r]);
    }
}
__device__ __forceinline__ void cvt4(const float* s, ushort_t* d, long blk, int tid) {
    long i = (blk * 256 + tid) * 4;
    float4 v = *(const float4*)(s + i);
    u16x4 o;
    o[0] = f2bf(v.x); o[1] = f2bf(v.y); o[2] = f2bf(v.z); o[3] = f2bf(v.w);
    *(u16x4*)(d + i) = o;
}

__global__ __launch_bounds__(256) void prep_k(
    const float* __restrict__ x, const float* __restrict__ y,
    const float* __restrict__ Wqx, const float* __restrict__ Wqy,
    const float* __restrict__ Wgs, const float* __restrict__ Wgc,
    const float* __restrict__ Wp,
    ushort_t* __restrict__ xb, ushort_t* __restrict__ yb,
    ushort_t* __restrict__ WqxT, ushort_t* __restrict__ WqyT,
    ushort_t* __restrict__ WgsT, ushort_t* __restrict__ WgcT,
    ushort_t* __restrict__ WpT)
{
    const int bid = blockIdx.x, tid = threadIdx.x;
    if (bid < 2048)      cvt4(x, xb, bid, tid);
    else if (bid < 2560) cvt4(y, yb, bid - 2048, tid);
    else if (bid < 3328) { int l = bid - 2560; transp32(Wqx, WqxT, 512, 1536, l % 48, l / 48, tid); }
    else if (bid < 4096) { int l = bid - 3328; transp32(Wqy, WqyT, 512, 1536, l % 48, l / 48, tid); }
    else if (bid < 4352) { int l = bid - 4096; transp32(Wgs, WgsT, 512, 512, l % 16, l / 16, tid); }
    else if (bid < 4608) { int l = bid - 4352; transp32(Wgc, WgcT, 512, 512, l % 16, l / 16, tid); }
    else                 { int l = bid - 4608; transp32(Wp, WpT, 512, 512, l % 16, l / 16, tid); }
}

// ---------------------------------------------------------------------------
// fused slice transposes: vxT | vyT | kyT | qyT  -> dst[z][d][S]
// vectorized (16B/lane both global sides), swizzled LDS tile.
// ---------------------------------------------------------------------------
__global__ __launch_bounds__(256) void vT_fused(
    const ushort_t* __restrict__ qkvx, const ushort_t* __restrict__ qkvy,
    ushort_t* __restrict__ vxT, ushort_t* __restrict__ vyT,
    ushort_t* __restrict__ kyT, ushort_t* __restrict__ qyT)
{
    const int bx = blockIdx.x, z = blockIdx.y, b = z >> 3, h = z & 7;
    const ushort_t* src; ushort_t* dst; int S, s0; long sB, dZ;
    if (bx < 32)      { src = qkvx + 1024; dst = vxT; S = TT;  sB = (long)TT * 1536;  dZ = (long)64 * TT;  s0 = bx * 64; }
    else if (bx < 40) { src = qkvy + 1024; dst = vyT; S = MMM; sB = (long)MMM * 1536; dZ = (long)64 * MMM; s0 = (bx - 32) * 64; }
    else if (bx < 48) { src = qkvy + 512;  dst = kyT; S = MMM; sB = (long)MMM * 1536; dZ = (long)64 * MMM; s0 = (bx - 40) * 64; }
    else              { src = qkvy;        dst = qyT; S = MMM; sB = (long)MMM * 1536; dZ = (long)64 * MMM; s0 = (bx - 48) * 64; }
    const ushort_t* sp = src + (long)b * sB + (long)h * 64;
    ushort_t* dp = dst + (long)z * dZ;
    __shared__ __align__(16) ushort_t t[64][80];
    const int tid = threadIdx.x;
#pragma unroll
    for (int p = 0; p < 2; ++p) {
        int id = tid + p * 256;
        int r = id >> 3, cc = (id & 7) * 8;
        int cs = cc ^ ((r >> 3) * 8);
        *(s8v*)&t[r][cs] = *(const s8v*)&sp[(long)(s0 + r) * 1536 + cc];
    }
    __syncthreads();
#pragma unroll
    for (int p = 0; p < 2; ++p) {
        int id = tid + p * 256;
        int d = id >> 3, cc = (id & 7) * 8;
        s8v o;
#pragma unroll
        for (int k = 0; k < 8; ++k) {
            int r = cc + k;
            o[k] = (short)t[r][d ^ ((r >> 3) * 8)];
        }
        *(s8v*)&dp[(long)d * S + s0 + cc] = o;
    }
}

// ---------------------------------------------------------------------------
// staging helpers (XOR-swizzled LDS layout, 16B/lane global_load_lds)
// ---------------------------------------------------------------------------
__device__ __forceinline__ void stage_rows128(const ushort_t* src, long k0,
                                              ushort_t* dstL, int w, int lane) {
#pragma unroll
    for (int n = 0; n < 4; ++n) {
        int f = w * 4096 + n * 1024 + lane * 16;
        int row = f >> 7;
        int blk_g = ((f & 127) >> 4) ^ (row & 7);
        gload16(src + (long)row * 512 + k0 + blk_g * 8, dstL + ((w * 4096 + n * 1024) >> 1));
    }
}
__device__ __forceinline__ void stage_rows64(const ushort_t* src, long k0,
                                             ushort_t* dstL, int w, int lane) {
#pragma unroll
    for (int n = 0; n < 2; ++n) {
        int f = w * 2048 + n * 1024 + lane * 16;
        int row = f >> 7;
        int blk_g = ((f & 127) >> 4) ^ (row & 7);
        gload16(src + (long)row * 512 + k0 + blk_g * 8, dstL + ((w * 2048 + n * 1024) >> 1));
    }
}

// ---------------------------------------------------------------------------
// Combined QKV NT GEMM: by<32 -> x branch (q cols pre-scaled by SCALE*log2e),
// by in [32,40) -> y branch. 128x128 tile, BK=64, double-buffered.
// ---------------------------------------------------------------------------
__global__ __launch_bounds__(256) void qkv_k(
    const ushort_t* __restrict__ xb, const ushort_t* __restrict__ yb,
    const ushort_t* __restrict__ WqxT, const ushort_t* __restrict__ WqyT,
    const float* __restrict__ bqx, const float* __restrict__ bqy,
    ushort_t* __restrict__ qkvx, ushort_t* __restrict__ qkvy)
{
    const int by = blockIdx.y;
    const ushort_t* A; const ushort_t* Bm; const float* bias; ushort_t* O;
    int r0, qcols;
    if (by < 32) { A = xb; Bm = WqxT; bias = bqx; O = qkvx; r0 = by * 128; qcols = 512; }
    else         { A = yb; Bm = WqyT; bias = bqy; O = qkvy; r0 = (by - 32) * 128; qcols = 0; }
    const int c0 = blockIdx.x * 128;
    const int tid = threadIdx.x, w = tid >> 6, lane = tid & 63;
    const int quad = lane >> 4, l15 = lane & 15;
    const int rowBase = (w >> 1) * 64, colBase = (w & 1) * 64;

    __shared__ __align__(16) ushort_t Al[2][128 * 64];
    __shared__ __align__(16) ushort_t Bl[2][128 * 64];

    const ushort_t* Ab = A + (long)r0 * 512;
    const ushort_t* Bb = Bm + (long)c0 * 512;

    f4 acc[4][4] = {};

    stage_rows128(Ab, 0, Al[0], w, lane);
    stage_rows128(Bb, 0, Bl[0], w, lane);
    __syncthreads();

    for (int kk = 0; kk < 8; ++kk) {
        const int cur = kk & 1;
        if (kk < 7) {
            stage_rows128(Ab, (kk + 1) * 64, Al[cur ^ 1], w, lane);
            stage_rows128(Bb, (kk + 1) * 64, Bl[cur ^ 1], w, lane);
        }
#pragma unroll
        for (int ks = 0; ks < 2; ++ks) {
            s8v af[4], bfr[4];
#pragma unroll
            for (int i = 0; i < 4; ++i) {
                int row = rowBase + 16 * i + l15;
                af[i] = *(const s8v*)&Al[cur][row * 64 + (((ks * 4 + quad) ^ (row & 7)) * 8)];
                int col = colBase + 16 * i + l15;
                bfr[i] = *(const s8v*)&Bl[cur][col * 64 + (((ks * 4 + quad) ^ (col & 7)) * 8)];
            }
#pragma unroll
            for (int i = 0; i < 4; ++i)
#pragma unroll
                for (int j = 0; j < 4; ++j)
                    acc[i][j] = __builtin_amdgcn_mfma_f32_16x16x32_bf16(af[i], bfr[j], acc[i][j], 0, 0, 0);
        }
        __syncthreads();
    }

#pragma unroll
    for (int i = 0; i < 4; ++i)
#pragma unroll
        for (int j = 0; j < 4; ++j)
#pragma unroll
            for (int r = 0; r < 4; ++r) {
                int row = r0 + rowBase + 16 * i + quad * 4 + r;
                int col = c0 + colBase + 16 * j + l15;
                float v = acc[i][j][r] + bias[col];
                if (col < qcols) v *= SCALE_L2E;   // fold SCALE*log2e into q_x
                O[(long)row * 1536 + col] = f2bf(v);
            }
}

// ---------------------------------------------------------------------------
// Proj NT GEMM. 64x64 tile (grid 8x64 = 512 blocks -> 2 blocks/CU),
// 3-slot ring + counted vmcnt single-barrier pipeline.
// ---------------------------------------------------------------------------
__global__ __launch_bounds__(256) void proj_k(
    const ushort_t* __restrict__ A, const ushort_t* __restrict__ Bm,
    float* __restrict__ O, const float* __restrict__ bias)
{
    const int r0 = blockIdx.y * 64, c0 = blockIdx.x * 64;
    const int tid = threadIdx.x, w = tid >> 6, lane = tid & 63;
    const int quad = lane >> 4, l15 = lane & 15;
    const int rowBase = (w >> 1) * 32, colBase = (w & 1) * 32;

    __shared__ __align__(16) ushort_t Al[3][64 * 64];
    __shared__ __align__(16) ushort_t Bl[3][64 * 64];

    const ushort_t* Ab = A + (long)r0 * 512;
    const ushort_t* Bb = Bm + (long)c0 * 512;

    f4 acc[2][2] = {};

    stage_rows64(Ab, 0, Al[0], w, lane);
    stage_rows64(Bb, 0, Bl[0], w, lane);
    stage_rows64(Ab, 64, Al[1], w, lane);
    stage_rows64(Bb, 64, Bl[1], w, lane);

    int cur = 0;
    for (int kk = 0; kk < 8; ++kk) {
        if (kk + 1 < 8) asm volatile("s_waitcnt vmcnt(4)" ::: "memory");
        else            asm volatile("s_waitcnt vmcnt(0)" ::: "memory");
        asm volatile("s_barrier" ::: "memory");
        if (kk + 2 < 8) {
            int s = cur + 2; if (s >= 3) s -= 3;
            stage_rows64(Ab, (kk + 2) * 64, Al[s], w, lane);
            stage_rows64(Bb, (kk + 2) * 64, Bl[s], w, lane);
        }
#pragma unroll
        for (int ks = 0; ks < 2; ++ks) {
            s8v af[2], bfr[2];
#pragma unroll
            for (int i = 0; i < 2; ++i) {
                int row = rowBase + 16 * i + l15;
                af[i] = *(const s8v*)&Al[cur][row * 64 + (((ks * 4 + quad) ^ (row & 7)) * 8)];
                int col = colBase + 16 * i + l15;
                bfr[i] = *(const s8v*)&Bl[cur][col * 64 + (((ks * 4 + quad) ^ (col & 7)) * 8)];
            }
#pragma unroll
            for (int i = 0; i < 2; ++i)
#pragma unroll
                for (int j = 0; j < 2; ++j)
                    acc[i][j] = __builtin_amdgcn_mfma_f32_16x16x32_bf16(af[i], bfr[j], acc[i][j], 0, 0, 0);
        }
        if (++cur == 3) cur = 0;
    }

#pragma unroll
    for (int i = 0; i < 2; ++i)
#pragma unroll
        for (int j = 0; j < 2; ++j)
#pragma unroll
            for (int r = 0; r < 4; ++r) {
                int row = r0 + rowBase + 16 * i + quad * 4 + r;
                int col = c0 + colBase + 16 * j + l15;
                O[(long)row * 512 + col] = acc[i][j][r] + bias[col];
            }
}

// ---------------------------------------------------------------------------
// Gt[z][d2][d1] = SCALE^2 * sum_m q_y[m,d2]*k_y[m,d1]  (q_x carries
// SCALE*log2e -> prod logits get SCALE^3*log2e total).
// 4 waves split the M=512 reduction (128 each), LDS tree-reduce.
// ---------------------------------------------------------------------------
__global__ __launch_bounds__(256) void gt_k(const ushort_t* __restrict__ qyT,
                                            const ushort_t* __restrict__ kyT,
                                            ushort_t* __restrict__ Gt)
{
    const int z = blockIdx.x;
    const int tid = threadIdx.x, w = tid >> 6, lane = tid & 63;
    const int quad = lane >> 4, l15 = lane & 15;
    const ushort_t* A  = qyT + (long)z * 64 * MMM;
    const ushort_t* Bm = kyT + (long)z * 64 * MMM;
    __shared__ float red[4][4096];
    f4 acc[4][4] = {};
    for (int kk = 0; kk < 4; ++kk) {
        const int ks = w * 4 + kk;
        s8v af[4], bfr[4];
#pragma unroll
        for (int i = 0; i < 4; ++i) {
            af[i]  = *(const s8v*)(A  + (long)(16 * i + l15) * MMM + ks * 32 + quad * 8);
            bfr[i] = *(const s8v*)(Bm + (long)(16 * i + l15) * MMM + ks * 32 + quad * 8);
        }
#pragma unroll
        for (int i = 0; i < 4; ++i)
#pragma unroll
            for (int j = 0; j < 4; ++j)
                acc[i][j] = __builtin_amdgcn_mfma_f32_16x16x32_bf16(af[i], bfr[j], acc[i][j], 0, 0, 0);
    }
#pragma unroll
    for (int i = 0; i < 4; ++i)
#pragma unroll
        for (int j = 0; j < 4; ++j)
            *(f4*)&red[w][(i * 4 + j) * 256 + lane * 4] = acc[i][j];
    __syncthreads();
    const float s2 = SCALE * SCALE;
#pragma unroll
    for (int j = 0; j < 4; ++j) {
        f4 s = *(const f4*)&red[0][(w * 4 + j) * 256 + lane * 4];
#pragma unroll
        for (int ww = 1; ww < 4; ++ww)
            s += *(const f4*)&red[ww][(w * 4 + j) * 256 + lane * 4];
#pragma unroll
        for (int r = 0; r < 4; ++r) {
            int d2 = 16 * w + quad * 4 + r, d1 = 16 * j + l15;
            Gt[(long)z * 4096 + d2 * 64 + d1] = f2bf(s2 * s[r]);
        }
    }
}

// ---------------------------------------------------------------------------
// Fused 3-stream flash, R16: UNIFORM blocks via linear-softmax split.
// Fixed-max softmax (p=2^v, l=sum p, O=sum P.V) is linear in KV tiles ->
// arbitrary KV partitions combine by addition. Pair p: qA=p, qB=31-p.
// Cost units (cross=1, causal=2): pair = 84.
//   half 0: qA complete (10+2p, final write) + qB prefix (32-2p) -> partial0
//   half 1: qB suffix (40 units) -> partial1
// All 512 blocks equal (40-42 units) -> flat 8 waves/CU, zero tail, no
// dispatch-order assumptions. combine_k sums partials, normalizes, writes
// qB rows. Partials fp32 -> bit-for-bit same arithmetic class as before.
// ---------------------------------------------------------------------------
__device__ __forceinline__ void stage_k64(const ushort_t* src, long rstride, int s0,
                                          ushort_t* Kl, int w, int lane) {
#pragma unroll
    for (int n = 0; n < 2; ++n) {
        int f = w * 2048 + n * 1024 + lane * 16;
        int row = f >> 7;
        int krow = ((row & 15) << 2) | (row >> 4);   // k-interleave permutation
        int blk = ((f & 127) >> 4) ^ (row & 7);
        gload16(src + (long)(s0 + krow) * rstride + blk * 8, &Kl[(w * 2048 + n * 1024) >> 1]);
    }
}
__device__ __forceinline__ void stage_v64(const ushort_t* src, long rstride, int s0,
                                          ushort_t* Vl, int w, int lane) {
#pragma unroll
    for (int n = 0; n < 2; ++n) {
        int f = w * 2048 + n * 1024 + lane * 16;
        int row = f >> 7;
        int blk = ((f & 127) >> 4) ^ (row & 7);
        gload16(src + (long)row * rstride + s0 + blk * 8, &Vl[(w * 2048 + n * 1024) >> 1]);
    }
}
__device__ __forceinline__ void qk8(f4 Sc[4], const s8v qf[2], const ushort_t* Kl,
                                    int quad, int l15) {
    __builtin_amdgcn_s_setprio(1);
#pragma unroll
    for (int ks = 0; ks < 2; ++ks)
#pragma unroll
        for (int c = 0; c < 4; ++c) {
            int row = 16 * c + l15;
            s8v bb = *(const s8v*)&Kl[row * 64 + (((ks * 4 + quad) ^ (row & 7)) * 8)];
            Sc[c] = __builtin_amdgcn_mfma_f32_16x16x32_bf16(qf[ks], bb, Sc[c], 0, 0, 0);
        }
    __builtin_amdgcn_s_setprio(0);
}
__device__ __forceinline__ void qk8_dual(f4 Ss[4], f4 Sp[4], const s8v qa[2], const s8v qb[2],
                                         const ushort_t* Kl, int quad, int l15) {
    __builtin_amdgcn_s_setprio(1);
#pragma unroll
    for (int ks = 0; ks < 2; ++ks)
#pragma unroll
        for (int c = 0; c < 4; ++c) {
            int row = 16 * c + l15;
            s8v bb = *(const s8v*)&Kl[row * 64 + (((ks * 4 + quad) ^ (row & 7)) * 8)];
            Ss[c] = __builtin_amdgcn_mfma_f32_16x16x32_bf16(qa[ks], bb, Ss[c], 0, 0, 0);
            Sp[c] = __builtin_amdgcn_mfma_f32_16x16x32_bf16(qb[ks], bb, Sp[c], 0, 0, 0);
        }
    __builtin_amdgcn_s_setprio(0);
}
// fixed-max softmax: p = 2^v (logits pre-scaled by log2e); lane-local l;
// P written as packed b64 (k-cols 4*l15..4*l15+3 consecutive after interleave)
__device__ __forceinline__ void smax0(const f4 Sc[4], float l_i[4], ushort_t* PlW,
                                      int diag, int trow0, int s0, int quad, int l15) {
#pragma unroll
    for (int r = 0; r < 4; ++r) {
        const int trow = trow0 + quad * 4 + r;
        u16x4 o;
#pragma unroll
        for (int c = 0; c < 4; ++c) {
            float v = Sc[c][r];
            if (diag && (s0 + 4 * l15 + c) > trow) v = -3e38f;
            float p = exp2_raw(v);
            l_i[r] += p;
            o[c] = f2bf(p);
        }
        *(u16x4*)&PlW[(quad * 4 + r) * 72 + 4 * l15] = o;
    }
}
__device__ __forceinline__ void pv8(f4 Oc[4], const ushort_t* PlW, const ushort_t* Vl,
                                    int quad, int l15) {
    __builtin_amdgcn_s_setprio(1);
#pragma unroll
    for (int ks = 0; ks < 2; ++ks) {
        s8v a = *(const s8v*)&PlW[l15 * 72 + ks * 32 + quad * 8];
#pragma unroll
        for (int c = 0; c < 4; ++c) {
            int row = 16 * c + l15;
            s8v bb = *(const s8v*)&Vl[row * 64 + (((ks * 4 + quad) ^ (row & 7)) * 8)];
            Oc[c] = __builtin_amdgcn_mfma_f32_16x16x32_bf16(a, bb, Oc[c], 0, 0, 0);
        }
    }
    __builtin_amdgcn_s_setprio(0);
}
__device__ __forceinline__ void pv8_dual(f4 Os[4], f4 Op[4], const ushort_t* Ps,
                                         const ushort_t* Pp, const ushort_t* Vl,
                                         int quad, int l15) {
    __builtin_amdgcn_s_setprio(1);
#pragma unroll
    for (int ks = 0; ks < 2; ++ks) {
        s8v as = *(const s8v*)&Ps[l15 * 72 + ks * 32 + quad * 8];
        s8v ap = *(const s8v*)&Pp[l15 * 72 + ks * 32 + quad * 8];
#pragma unroll
        for (int c = 0; c < 4; ++c) {
            int row = 16 * c + l15;
            s8v bb = *(const s8v*)&Vl[row * 64 + (((ks * 4 + quad) ^ (row & 7)) * 8)];
            Os[c] = __builtin_amdgcn_mfma_f32_16x16x32_bf16(as, bb, Os[c], 0, 0, 0);
            Op[c] = __builtin_amdgcn_mfma_f32_16x16x32_bf16(ap, bb, Op[c], 0, 0, 0);
        }
    }
    __builtin_amdgcn_s_setprio(0);
}
__device__ __forceinline__ void reduce16(float (&a)[4], float (&b)[4], float (&c)[4]) {
#pragma unroll
    for (int r = 0; r < 4; ++r)
#pragma unroll
        for (int mb = 1; mb < 16; mb <<= 1) {
            a[r] += __shfl_xor(a[r], mb, 64);
            b[r] += __shfl_xor(b[r], mb, 64);
            c[r] += __shfl_xor(c[r], mb, 64);
        }
}

// generic chunk processor: cross tiles [c0,c0+nc) then causal tiles [u0,u0+nu)
// of qtile qt. 3-slot ring, counted vmcnt, 1 barrier/tile. n = nc+nu >= 2.
__device__ __forceinline__ void run_chunk(
    const ushort_t* ky, const ushort_t* vy, const ushort_t* kx, const ushort_t* vx,
    const ushort_t* qx, const ushort_t* Gz,
    ushort_t (*Kl)[64 * 64], ushort_t (*Vl)[64 * 64],
    ushort_t* PlWs, ushort_t* PlWp,
    int qt, int c0, int nc, int u0, int nu,
    int w, int lane, int quad, int l15,
    f4 (&Occ)[4], f4 (&Ocs)[4], f4 (&Ocp)[4],
    float (&lc)[4], float (&ls)[4], float (&lp)[4])
{
    const int n = nc + nu;
    const int t0q = qt * 64;
    auto stage = [&](int ti, int slot) {
        if (ti < nc) {
            const int c = c0 + ti;
            stage_k64(ky, 1536, c * 64, Kl[slot], w, lane);
            stage_v64(vy, MMM, c * 64, Vl[slot], w, lane);
        } else {
            const int uu = u0 + ti - nc;
            stage_k64(kx, 1536, uu * 64, Kl[slot], w, lane);
            stage_v64(vx, TT, uu * 64, Vl[slot], w, lane);
        }
    };
    stage(0, 0);
    stage(1, 1);

    // Q frags; q~ = qx_scaled @ Gt^T (LDS roundtrip, wave-private P rows)
    const int qrow = t0q + 16 * w + l15;
    s8v qfx[2], qft[2];
    qfx[0] = *(const s8v*)(qx + (long)qrow * 1536 + quad * 8);
    qfx[1] = *(const s8v*)(qx + (long)qrow * 1536 + 32 + quad * 8);
    if (nu > 0) {
        f4 qa[4] = {};
#pragma unroll
        for (int ks = 0; ks < 2; ++ks)
#pragma unroll
            for (int j = 0; j < 4; ++j) {
                s8v bb = *(const s8v*)(Gz + (4 * l15 + j) * 64 + ks * 32 + quad * 8);
                qa[j] = __builtin_amdgcn_mfma_f32_16x16x32_bf16(qfx[ks], bb, qa[j], 0, 0, 0);
            }
#pragma unroll
        for (int r = 0; r < 4; ++r) {
            u16x4 o;
#pragma unroll
            for (int j = 0; j < 4; ++j) o[j] = f2bf(qa[j][r]);
            *(u16x4*)&PlWs[(quad * 4 + r) * 72 + 4 * l15] = o;
        }
        qft[0] = *(const s8v*)&PlWs[l15 * 72 + quad * 8];
        qft[1] = *(const s8v*)&PlWs[l15 * 72 + 32 + quad * 8];
    } else {
        qft[0] = qfx[0]; qft[1] = qfx[1];
    }
    // tiles 0,1 resident in every wave (incl. prior chunk's stores drained)
    asm volatile("s_waitcnt vmcnt(0)" ::: "memory");
    asm volatile("s_barrier" ::: "memory");

    int cur = 0;
    for (int ti = 0; ti < n; ++ti) {
        if (ti > 0) {
            if (ti + 1 < n) asm volatile("s_waitcnt vmcnt(4)" ::: "memory");
            else            asm volatile("s_waitcnt vmcnt(0)" ::: "memory");
            asm volatile("s_barrier" ::: "memory");
        }
        if (ti + 2 < n) {
            int sl = cur + 2; if (sl >= 3) sl -= 3;
            stage(ti + 2, sl);
        }
        if (ti < nc) {
            f4 Sc[4] = {};
            qk8(Sc, qfx, Kl[cur], quad, l15);
            smax0(Sc, lc, PlWs, 0, 0, 0, quad, l15);
            pv8(Occ, PlWs, Vl[cur], quad, l15);
        } else {
            const int uu = u0 + ti - nc;
            const int diag = (uu == qt);
            f4 Ss[4] = {}, Sp[4] = {};
            qk8_dual(Ss, Sp, qfx, qft, Kl[cur], quad, l15);
            smax0(Ss, ls, PlWs, diag, t0q + 16 * w, uu * 64, quad, l15);
            smax0(Sp, lp, PlWp, diag, t0q + 16 * w, uu * 64, quad, l15);
            pv8_dual(Ocs, Ocp, PlWs, PlWp, Vl[cur], quad, l15);
        }
        if (++cur == 3) cur = 0;
    }
    // all waves done reading ring slots before caller re-stages them
    asm volatile("s_barrier" ::: "memory");
}

__global__ __launch_bounds__(256, 2) void flash_fused(
    const ushort_t* __restrict__ qkvx, const ushort_t* __restrict__ qkvy,
    const ushort_t* __restrict__ Gt, const ushort_t* __restrict__ vxT,
    const ushort_t* __restrict__ vyT,
    ushort_t* __restrict__ cval, ushort_t* __restrict__ sval,
    float* __restrict__ partO, float* __restrict__ partL)
{
    const int z = blockIdx.y, b = z >> 3, h = z & 7;
    const int sblk = blockIdx.x, p = sblk >> 1, half = sblk & 1;
    const int qA = p, qB = 31 - p;
    const ushort_t* qx = qkvx + (long)b * (TT * 1536) + h * 64;   // pre-scaled SCALE*log2e
    const ushort_t* kx = qx + 512;
    const ushort_t* ky = qkvy + (long)b * (MMM * 1536) + 512 + h * 64;
    const ushort_t* Gz = Gt + (long)z * 4096;
    const ushort_t* vx = vxT + (long)z * (64 * TT);
    const ushort_t* vy = vyT + (long)z * (64 * MMM);

    const int tid = threadIdx.x, w = tid >> 6, lane = tid & 63;
    const int quad = lane >> 4, l15 = lane & 15;

    __shared__ __align__(16) ushort_t Kl[3][64 * 64];
    __shared__ __align__(16) ushort_t Vl[3][64 * 64];
    __shared__ __align__(16) ushort_t Pl[2][4 * 16 * 72];
    ushort_t* PlWs = &Pl[0][w * 1152];
    ushort_t* PlWp = &Pl[1][w * 1152];

    // qB prefix split point (units: cross=1, causal=2; half0 extra = 32-2p)
    int cA2, uA2;
    if (p >= 12) { cA2 = 32 - 2 * p; uA2 = 0; }
    else         { cA2 = 8;          uA2 = 12 - p; }

    const long obase = (long)b * (TT * CC) + h * 64;
    const long inst = (long)z * 16 + (qB - 16);
    float* po = partO + (inst * 2 + half) * 3 * 4096;
    float* pl = partL + (inst * 2 + half) * 3 * 64;

    if (half == 0) {
        {   // ---- chunk 1: qtile qA complete -> final write ----
            f4 Occ[4] = {}, Ocs[4] = {}, Ocp[4] = {};
            float lc[4] = {}, ls[4] = {}, lp[4] = {};
            run_chunk(ky, vy, kx, vx, qx, Gz, Kl, Vl, PlWs, PlWp,
                      qA, 0, 8, 0, qA + 1, w, lane, quad, l15,
                      Occ, Ocs, Ocp, lc, ls, lp);
            reduce16(lc, ls, lp);
#pragma unroll
            for (int r = 0; r < 4; ++r) {
                int row = qA * 64 + 16 * w + quad * 4 + r;
                float ic = 1.f / lc[r], ip = 1.f / lp[r], isv = 1.f / ls[r];
#pragma unroll
                for (int c = 0; c < 4; ++c) {
                    long idx = obase + (long)row * CC + 16 * c + l15;
                    cval[idx] = f2bf(Occ[c][r] * ic + Ocp[c][r] * ip);
                    sval[idx] = f2bf(Ocs[c][r] * isv);
                }
            }
        }
        {   // ---- chunk 2: qB prefix -> partial 0 ----
            f4 Occ[4] = {}, Ocs[4] = {}, Ocp[4] = {};
            float lc[4] = {}, ls[4] = {}, lp[4] = {};
            run_chunk(ky, vy, kx, vx, qx, Gz, Kl, Vl, PlWs, PlWp,
                      qB, 0, cA2, 0, uA2, w, lane, quad, l15,
                      Occ, Ocs, Ocp, lc, ls, lp);
            reduce16(lc, ls, lp);
#pragma unroll
            for (int r = 0; r < 4; ++r) {
                const int row = 16 * w + quad * 4 + r;
#pragma unroll
                for (int c = 0; c < 4; ++c) {
                    const int col = 16 * c + l15;
                    po[row * 64 + col]        = Occ[c][r];
                    po[4096 + row * 64 + col] = Ocs[c][r];
                    po[8192 + row * 64 + col] = Ocp[c][r];
                }
                if (l15 == 0) { pl[row] = lc[r]; pl[64 + row] = ls[r]; pl[128 + row] = lp[r]; }
            }
        }
    } else {
        // ---- qB suffix -> partial 1 ----
        f4 Occ[4] = {}, Ocs[4] = {}, Ocp[4] = {};
        float lc[4] = {}, ls[4] = {}, lp[4] = {};
        run_chunk(ky, vy, kx, vx, qx, Gz, Kl, Vl, PlWs, PlWp,
                  qB, cA2, 8 - cA2, uA2, (qB + 1) - uA2, w, lane, quad, l15,
                  Occ, Ocs, Ocp, lc, ls, lp);
        reduce16(lc, ls, lp);
#pragma unroll
        for (int r = 0; r < 4; ++r) {
            const int row = 16 * w + quad * 4 + r;
#pragma unroll
            for (int c = 0; c < 4; ++c) {
                const int col = 16 * c + l15;
                po[row * 64 + col]        = Occ[c][r];
                po[4096 + row * 64 + col] = Ocs[c][r];
                po[8192 + row * 64 + col] = Ocp[c][r];
            }
            if (l15 == 0) { pl[row] = lc[r]; pl[64 + row] = ls[r]; pl[128 + row] = lp[r]; }
        }
    }
}

// ---------------------------------------------------------------------------
// combine_k: cval/sval rows of split qtiles (qB=16..31) = normalize(P0+P1).
// 256 blocks x 256 threads; thread -> (row = tid/4, 16 cols).
// ---------------------------------------------------------------------------
__global__ __launch_bounds__(256) void combine_k(
    const float* __restrict__ partO, const float* __restrict__ partL,
    ushort_t* __restrict__ cval, ushort_t* __restrict__ sval)
{
    const int inst = blockIdx.x;
    const int z = inst >> 4, qb = 16 + (inst & 15);
    const int b = z >> 3, h = z & 7;
    const int tid = threadIdx.x;
    const int row = tid >> 2, cq = (tid & 3) * 16;
    const float* p0 = partO + ((long)inst * 2 + 0) * 3 * 4096;
    const float* p1 = partO + ((long)inst * 2 + 1) * 3 * 4096;
    const float* l0 = partL + ((long)inst * 2 + 0) * 3 * 64;
    const float* l1 = partL + ((long)inst * 2 + 1) * 3 * 64;
    const float ic  = 1.f / (l0[row] + l1[row]);
    const float isv = 1.f / (l0[64 + row] + l1[64 + row]);
    const float ip  = 1.f / (l0[128 + row] + l1[128 + row]);
    const long ob = (long)b * (TT * CC) + h * 64 + (long)(qb * 64 + row) * CC + cq;
    u16x4 vc[4], vs[4];
#pragma unroll
    for (int k = 0; k < 4; ++k) {
        const int e = row * 64 + cq + k * 4;
        f4 oc = *(const f4*)&p0[e]        + *(const f4*)&p1[e];
        f4 os = *(const f4*)&p0[4096 + e] + *(const f4*)&p1[4096 + e];
        f4 op = *(const f4*)&p0[8192 + e] + *(const f4*)&p1[8192 + e];
#pragma unroll
        for (int j = 0; j < 4; ++j) {
            vc[k][j] = f2bf(oc[j] * ic + op[j] * ip);
            vs[k][j] = f2bf(os[j] * isv);
        }
    }
#pragma unroll
    for (int k = 0; k < 4; ++k) {
        *(u16x4*)&cval[ob + k * 4] = vc[k];
        *(u16x4*)&sval[ob + k * 4] = vs[k];
    }
}

// ---------------------------------------------------------------------------
// Fused gate. 64x64 tile (grid 8x64 = 512 blocks), 16 flattened k-steps
// (2 passes x 8), 3-slot ring + counted vmcnt.
// ---------------------------------------------------------------------------
__global__ __launch_bounds__(256) void gate_gemm(
    const ushort_t* __restrict__ sval, const ushort_t* __restrict__ cvalb,
    const ushort_t* __restrict__ WgsT, const ushort_t* __restrict__ WgcT,
    const float* __restrict__ bgs, const float* __restrict__ bgc,
    ushort_t* __restrict__ tmpb)
{
    const int r0 = blockIdx.y * 64, c0 = blockIdx.x * 64;
    const int tid = threadIdx.x, w = tid >> 6, lane = tid & 63;
    const int quad = lane >> 4, l15 = lane & 15;
    const int rowBase = (w >> 1) * 32, colBase = (w & 1) * 32;

    __shared__ __align__(16) ushort_t Al[3][64 * 64];
    __shared__ __align__(16) ushort_t Bl[3][64 * 64];

    const ushort_t* Ap[2] = { sval + (long)r0 * 512, cvalb + (long)r0 * 512 };
    const ushort_t* Bp[2] = { WgsT + (long)c0 * 512, WgcT + (long)c0 * 512 };

    f4 acc1[2][2] = {}, acc2[2][2] = {};

    stage_rows64(Ap[0], 0, Al[0], w, lane);
    stage_rows64(Bp[0], 0, Bl[0], w, lane);
    stage_rows64(Ap[0], 64, Al[1], w, lane);
    stage_rows64(Bp[0], 64, Bl[1], w, lane);

    int cur = 0;
    for (int st = 0; st < 16; ++st) {
        if (st + 1 < 16) asm volatile("s_waitcnt vmcnt(4)" ::: "memory");
        else             asm volatile("s_waitcnt vmcnt(0)" ::: "memory");
        asm volatile("s_barrier" ::: "memory");
        if (st + 2 < 16) {
            int s = cur + 2; if (s >= 3) s -= 3;
            const int nx = st + 2, p = nx >> 3;
            stage_rows64(Ap[p], (nx & 7) * 64, Al[s], w, lane);
            stage_rows64(Bp[p], (nx & 7) * 64, Bl[s], w, lane);
        }
#pragma unroll
        for (int ks = 0; ks < 2; ++ks) {
            s8v af[2], bfr[2];
#pragma unroll
            for (int i = 0; i < 2; ++i) {
                int row = rowBase + 16 * i + l15;
                af[i] = *(const s8v*)&Al[cur][row * 64 + (((ks * 4 + quad) ^ (row & 7)) * 8)];
                int col = colBase + 16 * i + l15;
                bfr[i] = *(const s8v*)&Bl[cur][col * 64 + (((ks * 4 + quad) ^ (col & 7)) * 8)];
            }
            if (st < 8) {
#pragma unroll
                for (int i = 0; i < 2; ++i)
#pragma unroll
                    for (int j = 0; j < 2; ++j)
                        acc1[i][j] = __builtin_amdgcn_mfma_f32_16x16x32_bf16(af[i], bfr[j], acc1[i][j], 0, 0, 0);
            } else {
#pragma unroll
                for (int i = 0; i < 2; ++i)
#pragma unroll
                    for (int j = 0; j < 2; ++j)
                        acc2[i][j] = __builtin_amdgcn_mfma_f32_16x16x32_bf16(af[i], bfr[j], acc2[i][j], 0, 0, 0);
            }
        }
        if (++cur == 3) cur = 0;
    }

#pragma unroll
    for (int i = 0; i < 2; ++i)
#pragma unroll
        for (int j = 0; j < 2; ++j)
#pragma unroll
            for (int r = 0; r < 4; ++r) {
                int row = r0 + rowBase + 16 * i + quad * 4 + r;
                int col = c0 + colBase + 16 * j + l15;
                long idx = (long)row * 512 + col;
                float g1 = 1.f / (1.f + __expf(-(acc1[i][j][r] + bgs[col])));
                float g2 = 1.f / (1.f + __expf(-(acc2[i][j][r] + bgc[col])));
                tmpb[idx] = f2bf(g1 * bf2f(cvalb[idx]) + g2 * bf2f(sval[idx]));
            }
}

extern "C" void kernel_launch(void* const* d_in, const int* in_sizes, int n_in,
                              void* d_out, int out_size, void* d_ws, size_t ws_size,
                              hipStream_t stream) {
    const float* x      = (const float*)d_in[0];
    const float* y      = (const float*)d_in[1];
    // d_in[2] = attn_x_mask (deterministic tril) -> causal branch
    const float* Wqkv_x = (const float*)d_in[3];
    const float* bqkv_x = (const float*)d_in[4];
    const float* Wqkv_y = (const float*)d_in[5];
    const float* bqkv_y = (const float*)d_in[6];
    const float* Wgs    = (const float*)d_in[7];
    const float* bgs    = (const float*)d_in[8];
    const float* Wgc    = (const float*)d_in[9];
    const float* bgc    = (const float*)d_in[10];
    const float* Wp     = (const float*)d_in[11];
    const float* bp     = (const float*)d_in[12];
    float* out = (float*)d_out;

    // ---- workspace (bf16 shorts + fp32 partials), ~71 MB ----
    ushort_t* u = (ushort_t*)d_ws;
    long o = 0;
    ushort_t* xb    = u + o; o += (long)BB * TT * CC;
    ushort_t* yb    = u + o; o += (long)BB * MMM * CC;
    ushort_t* WqxT  = u + o; o += 1536L * 512;
    ushort_t* WqyT  = u + o; o += 1536L * 512;
    ushort_t* WgsT  = u + o; o += 512L * 512;
    ushort_t* WgcT  = u + o; o += 512L * 512;
    ushort_t* WpT   = u + o; o += 512L * 512;
    ushort_t* qkvx  = u + o; o += (long)BB * TT * 1536;
    ushort_t* qkvy  = u + o; o += (long)BB * MMM * 1536;
    ushort_t* vxT   = u + o; o += (long)BB * HH * DD * TT;
    ushort_t* vyT   = u + o; o += (long)BB * HH * DD * MMM;
    ushort_t* kyT   = u + o; o += (long)BB * HH * DD * MMM;
    ushort_t* qyT   = u + o; o += (long)BB * HH * DD * MMM;
    ushort_t* Gt    = u + o; o += 16L * 64 * 64;
    ushort_t* cvalb = u + o; o += (long)BB * TT * CC;
    ushort_t* sval  = u + o; o += (long)BB * TT * CC;
    ushort_t* tmpb  = u + o; o += (long)BB * TT * CC;
    // fp32 split-qtile partials: [inst=256][half=2][stream=3][64][64] + l
    float* partO = (float*)(u + o); o += 256L * 2 * 3 * 4096 * 2;
    float* partL = (float*)(u + o); o += 256L * 2 * 3 * 64 * 2;

    dim3 blk(256);

    // 1) prep: conversions + weight transposes
    prep_k<<<dim3(4864), blk, 0, stream>>>(x, y, Wqkv_x, Wqkv_y, Wgs, Wgc, Wp,
                                           xb, yb, WqxT, WqyT, WgsT, WgcT, WpT);

    // 2) combined qkv projections (q_x pre-scaled by SCALE*log2e)
    qkv_k<<<dim3(12, 40), blk, 0, stream>>>(xb, yb, WqxT, WqyT, bqkv_x, bqkv_y, qkvx, qkvy);

    // 3) fused slice transposes (vectorized)
    vT_fused<<<dim3(56, 16), blk, 0, stream>>>(qkvx, qkvy, vxT, vyT, kyT, qyT);

    // 4) Gt = SCALE^2 * Q_y^T K_y (4-wave split-M + LDS reduce)
    gt_k<<<dim3(16), blk, 0, stream>>>(qyT, kyT, Gt);

    // 5) fused 3-stream flash — uniform split blocks (all 512 equal work)
    flash_fused<<<dim3(32, 16), blk, 0, stream>>>(qkvx, qkvy, Gt, vxT, vyT,
                                                  cvalb, sval, partO, partL);

    // 5b) combine split-qtile partials -> cval/sval rows 1024..2047 per (b,h)
    combine_k<<<dim3(256), blk, 0, stream>>>(partO, partL, cvalb, sval);

    // 6) fused gates + combine (64x64 tile, 512 blocks, 3-ring pipeline)
    gate_gemm<<<dim3(8, 64), blk, 0, stream>>>(sval, cvalb, WgsT, WgcT, bgs, bgc, tmpb);

    // 7) out = tmpb @ Wp + bp (fp32, 64x64 tile, 512 blocks, 3-ring pipeline)
    proj_k<<<dim3(8, 64), blk, 0, stream>>>(tmpb, WpT, out, bp);
}

// Round 5
// 215.794 us; speedup vs baseline: 1.0117x; 1.0117x over previous
//
#include <hip/hip_runtime.h>
#include <hip/hip_bf16.h>

typedef unsigned short ushort_t;
typedef __attribute__((ext_vector_type(8))) short s8v;   // 8 bf16 = 4 VGPR (MFMA A/B frag)
typedef __attribute__((ext_vector_type(4))) float f4;    // 4 fp32 acc (MFMA C/D frag)
typedef __attribute__((ext_vector_type(4))) unsigned short u16x4;

// Problem constants: B=2, T=2048, M=512, C=512, H=8, D=64
#define BB 2
#define TT 2048
#define MMM 512
#define CC 512
#define HH 8
#define DD 64
#define SCALE 0.125f
// SCALE * log2(e): folded into q_x so softmax uses bare v_exp_f32 (2^x)
#define SCALE_L2E 0.18033688011112042f

__device__ __forceinline__ ushort_t f2bf(float v) {
    __hip_bfloat16 h = __float2bfloat16(v);
    return *reinterpret_cast<ushort_t*>(&h);
}
__device__ __forceinline__ float bf2f(ushort_t u) {
    __hip_bfloat16 h;
    *reinterpret_cast<ushort_t*>(&h) = u;
    return __bfloat162float(h);
}
// bare 2^x (v_exp_f32). Inputs pre-scaled by log2(e).
__device__ __forceinline__ float exp2_raw(float v) {
    float p;
    asm("v_exp_f32 %0, %1" : "=v"(p) : "v"(v));
    return p;
}

// async global->LDS, 16B per lane. LDS dst = wave-uniform base + lane*16.
__device__ __forceinline__ void gload16(const void* g, void* l) {
    __builtin_amdgcn_global_load_lds((const __attribute__((address_space(1))) void*)g,
                                     (__attribute__((address_space(3))) void*)l, 16, 0, 0);
}

// ---------------------------------------------------------------------------
// prep_k: x/y fp32->bf16 (float4-vectorized) + 5 weight transposes.
// ---------------------------------------------------------------------------
__device__ __forceinline__ void transp32(const float* W, ushort_t* WT, int K, int N,
                                         int bx, int by, int tid) {
    const int k0 = by * 32, n0 = bx * 32;
    __shared__ float t[32][33];
    for (int i = tid; i < 1024; i += 256) {
        int r = i >> 5, c = i & 31;
        t[r][c] = W[(long)(k0 + r) * N + n0 + c];
    }
    __syncthreads();
    for (int i = tid; i < 1024; i += 256) {
        int r = i >> 5, c = i & 31;
        WT[(long)(n0 + r) * K + k0 + c] = f2bf(t[c][r]);
    }
}
__device__ __forceinline__ void cvt4(const float* s, ushort_t* d, long blk, int tid) {
    long i = (blk * 256 + tid) * 4;
    float4 v = *(const float4*)(s + i);
    u16x4 o;
    o[0] = f2bf(v.x); o[1] = f2bf(v.y); o[2] = f2bf(v.z); o[3] = f2bf(v.w);
    *(u16x4*)(d + i) = o;
}

__global__ __launch_bounds__(256) void prep_k(
    const float* __restrict__ x, const float* __restrict__ y,
    const float* __restrict__ Wqx, const float* __restrict__ Wqy,
    const float* __restrict__ Wgs, const float* __restrict__ Wgc,
    const float* __restrict__ Wp,
    ushort_t* __restrict__ xb, ushort_t* __restrict__ yb,
    ushort_t* __restrict__ WqxT, ushort_t* __restrict__ WqyT,
    ushort_t* __restrict__ WgsT, ushort_t* __restrict__ WgcT,
    ushort_t* __restrict__ WpT)
{
    const int bid = blockIdx.x, tid = threadIdx.x;
    if (bid < 2048)      cvt4(x, xb, bid, tid);
    else if (bid < 2560) cvt4(y, yb, bid - 2048, tid);
    else if (bid < 3328) { int l = bid - 2560; transp32(Wqx, WqxT, 512, 1536, l % 48, l / 48, tid); }
    else if (bid < 4096) { int l = bid - 3328; transp32(Wqy, WqyT, 512, 1536, l % 48, l / 48, tid); }
    else if (bid < 4352) { int l = bid - 4096; transp32(Wgs, WgsT, 512, 512, l % 16, l / 16, tid); }
    else if (bid < 4608) { int l = bid - 4352; transp32(Wgc, WgcT, 512, 512, l % 16, l / 16, tid); }
    else                 { int l = bid - 4608; transp32(Wp, WpT, 512, 512, l % 16, l / 16, tid); }
}

// ---------------------------------------------------------------------------
// fused slice transposes: vxT | vyT | kyT | qyT  -> dst[z][d][S]
// vectorized (16B/lane both global sides), swizzled LDS tile.
// ---------------------------------------------------------------------------
__global__ __launch_bounds__(256) void vT_fused(
    const ushort_t* __restrict__ qkvx, const ushort_t* __restrict__ qkvy,
    ushort_t* __restrict__ vxT, ushort_t* __restrict__ vyT,
    ushort_t* __restrict__ kyT, ushort_t* __restrict__ qyT)
{
    const int bx = blockIdx.x, z = blockIdx.y, b = z >> 3, h = z & 7;
    const ushort_t* src; ushort_t* dst; int S, s0; long sB, dZ;
    if (bx < 32)      { src = qkvx + 1024; dst = vxT; S = TT;  sB = (long)TT * 1536;  dZ = (long)64 * TT;  s0 = bx * 64; }
    else if (bx < 40) { src = qkvy + 1024; dst = vyT; S = MMM; sB = (long)MMM * 1536; dZ = (long)64 * MMM; s0 = (bx - 32) * 64; }
    else if (bx < 48) { src = qkvy + 512;  dst = kyT; S = MMM; sB = (long)MMM * 1536; dZ = (long)64 * MMM; s0 = (bx - 40) * 64; }
    else              { src = qkvy;        dst = qyT; S = MMM; sB = (long)MMM * 1536; dZ = (long)64 * MMM; s0 = (bx - 48) * 64; }
    const ushort_t* sp = src + (long)b * sB + (long)h * 64;
    ushort_t* dp = dst + (long)z * dZ;
    __shared__ __align__(16) ushort_t t[64][80];
    const int tid = threadIdx.x;
#pragma unroll
    for (int p = 0; p < 2; ++p) {
        int id = tid + p * 256;
        int r = id >> 3, cc = (id & 7) * 8;
        int cs = cc ^ ((r >> 3) * 8);
        *(s8v*)&t[r][cs] = *(const s8v*)&sp[(long)(s0 + r) * 1536 + cc];
    }
    __syncthreads();
#pragma unroll
    for (int p = 0; p < 2; ++p) {
        int id = tid + p * 256;
        int d = id >> 3, cc = (id & 7) * 8;
        s8v o;
#pragma unroll
        for (int k = 0; k < 8; ++k) {
            int r = cc + k;
            o[k] = (short)t[r][d ^ ((r >> 3) * 8)];
        }
        *(s8v*)&dp[(long)d * S + s0 + cc] = o;
    }
}

// ---------------------------------------------------------------------------
// staging helpers (XOR-swizzled LDS layout, 16B/lane global_load_lds)
// ---------------------------------------------------------------------------
__device__ __forceinline__ void stage_rows128(const ushort_t* src, long k0,
                                              ushort_t* dstL, int w, int lane) {
#pragma unroll
    for (int n = 0; n < 4; ++n) {
        int f = w * 4096 + n * 1024 + lane * 16;
        int row = f >> 7;
        int blk_g = ((f & 127) >> 4) ^ (row & 7);
        gload16(src + (long)row * 512 + k0 + blk_g * 8, dstL + ((w * 4096 + n * 1024) >> 1));
    }
}
__device__ __forceinline__ void stage_rows64(const ushort_t* src, long k0,
                                             ushort_t* dstL, int w, int lane) {
#pragma unroll
    for (int n = 0; n < 2; ++n) {
        int f = w * 2048 + n * 1024 + lane * 16;
        int row = f >> 7;
        int blk_g = ((f & 127) >> 4) ^ (row & 7);
        gload16(src + (long)row * 512 + k0 + blk_g * 8, dstL + ((w * 2048 + n * 1024) >> 1));
    }
}

// ---------------------------------------------------------------------------
// Combined QKV NT GEMM: by<32 -> x branch (q cols pre-scaled by SCALE*log2e),
// by in [32,40) -> y branch. 128x128 tile, BK=64, double-buffered.
// ---------------------------------------------------------------------------
__global__ __launch_bounds__(256) void qkv_k(
    const ushort_t* __restrict__ xb, const ushort_t* __restrict__ yb,
    const ushort_t* __restrict__ WqxT, const ushort_t* __restrict__ WqyT,
    const float* __restrict__ bqx, const float* __restrict__ bqy,
    ushort_t* __restrict__ qkvx, ushort_t* __restrict__ qkvy)
{
    const int by = blockIdx.y;
    const ushort_t* A; const ushort_t* Bm; const float* bias; ushort_t* O;
    int r0, qcols;
    if (by < 32) { A = xb; Bm = WqxT; bias = bqx; O = qkvx; r0 = by * 128; qcols = 512; }
    else         { A = yb; Bm = WqyT; bias = bqy; O = qkvy; r0 = (by - 32) * 128; qcols = 0; }
    const int c0 = blockIdx.x * 128;
    const int tid = threadIdx.x, w = tid >> 6, lane = tid & 63;
    const int quad = lane >> 4, l15 = lane & 15;
    const int rowBase = (w >> 1) * 64, colBase = (w & 1) * 64;

    __shared__ __align__(16) ushort_t Al[2][128 * 64];
    __shared__ __align__(16) ushort_t Bl[2][128 * 64];

    const ushort_t* Ab = A + (long)r0 * 512;
    const ushort_t* Bb = Bm + (long)c0 * 512;

    f4 acc[4][4] = {};

    stage_rows128(Ab, 0, Al[0], w, lane);
    stage_rows128(Bb, 0, Bl[0], w, lane);
    __syncthreads();

    for (int kk = 0; kk < 8; ++kk) {
        const int cur = kk & 1;
        if (kk < 7) {
            stage_rows128(Ab, (kk + 1) * 64, Al[cur ^ 1], w, lane);
            stage_rows128(Bb, (kk + 1) * 64, Bl[cur ^ 1], w, lane);
        }
#pragma unroll
        for (int ks = 0; ks < 2; ++ks) {
            s8v af[4], bfr[4];
#pragma unroll
            for (int i = 0; i < 4; ++i) {
                int row = rowBase + 16 * i + l15;
                af[i] = *(const s8v*)&Al[cur][row * 64 + (((ks * 4 + quad) ^ (row & 7)) * 8)];
                int col = colBase + 16 * i + l15;
                bfr[i] = *(const s8v*)&Bl[cur][col * 64 + (((ks * 4 + quad) ^ (col & 7)) * 8)];
            }
#pragma unroll
            for (int i = 0; i < 4; ++i)
#pragma unroll
                for (int j = 0; j < 4; ++j)
                    acc[i][j] = __builtin_amdgcn_mfma_f32_16x16x32_bf16(af[i], bfr[j], acc[i][j], 0, 0, 0);
        }
        __syncthreads();
    }

#pragma unroll
    for (int i = 0; i < 4; ++i)
#pragma unroll
        for (int j = 0; j < 4; ++j)
#pragma unroll
            for (int r = 0; r < 4; ++r) {
                int row = r0 + rowBase + 16 * i + quad * 4 + r;
                int col = c0 + colBase + 16 * j + l15;
                float v = acc[i][j][r] + bias[col];
                if (col < qcols) v *= SCALE_L2E;   // fold SCALE*log2e into q_x
                O[(long)row * 1536 + col] = f2bf(v);
            }
}

// ---------------------------------------------------------------------------
// Proj NT GEMM. 64x64 tile (grid 8x64 = 512 blocks -> 2 blocks/CU),
// 3-slot ring + counted vmcnt single-barrier pipeline.
// ---------------------------------------------------------------------------
__global__ __launch_bounds__(256) void proj_k(
    const ushort_t* __restrict__ A, const ushort_t* __restrict__ Bm,
    float* __restrict__ O, const float* __restrict__ bias)
{
    const int r0 = blockIdx.y * 64, c0 = blockIdx.x * 64;
    const int tid = threadIdx.x, w = tid >> 6, lane = tid & 63;
    const int quad = lane >> 4, l15 = lane & 15;
    const int rowBase = (w >> 1) * 32, colBase = (w & 1) * 32;

    __shared__ __align__(16) ushort_t Al[3][64 * 64];
    __shared__ __align__(16) ushort_t Bl[3][64 * 64];

    const ushort_t* Ab = A + (long)r0 * 512;
    const ushort_t* Bb = Bm + (long)c0 * 512;

    f4 acc[2][2] = {};

    stage_rows64(Ab, 0, Al[0], w, lane);
    stage_rows64(Bb, 0, Bl[0], w, lane);
    stage_rows64(Ab, 64, Al[1], w, lane);
    stage_rows64(Bb, 64, Bl[1], w, lane);

    int cur = 0;
    for (int kk = 0; kk < 8; ++kk) {
        if (kk + 1 < 8) asm volatile("s_waitcnt vmcnt(4)" ::: "memory");
        else            asm volatile("s_waitcnt vmcnt(0)" ::: "memory");
        asm volatile("s_barrier" ::: "memory");
        if (kk + 2 < 8) {
            int s = cur + 2; if (s >= 3) s -= 3;
            stage_rows64(Ab, (kk + 2) * 64, Al[s], w, lane);
            stage_rows64(Bb, (kk + 2) * 64, Bl[s], w, lane);
        }
#pragma unroll
        for (int ks = 0; ks < 2; ++ks) {
            s8v af[2], bfr[2];
#pragma unroll
            for (int i = 0; i < 2; ++i) {
                int row = rowBase + 16 * i + l15;
                af[i] = *(const s8v*)&Al[cur][row * 64 + (((ks * 4 + quad) ^ (row & 7)) * 8)];
                int col = colBase + 16 * i + l15;
                bfr[i] = *(const s8v*)&Bl[cur][col * 64 + (((ks * 4 + quad) ^ (col & 7)) * 8)];
            }
#pragma unroll
            for (int i = 0; i < 2; ++i)
#pragma unroll
                for (int j = 0; j < 2; ++j)
                    acc[i][j] = __builtin_amdgcn_mfma_f32_16x16x32_bf16(af[i], bfr[j], acc[i][j], 0, 0, 0);
        }
        if (++cur == 3) cur = 0;
    }

#pragma unroll
    for (int i = 0; i < 2; ++i)
#pragma unroll
        for (int j = 0; j < 2; ++j)
#pragma unroll
            for (int r = 0; r < 4; ++r) {
                int row = r0 + rowBase + 16 * i + quad * 4 + r;
                int col = c0 + colBase + 16 * j + l15;
                O[(long)row * 512 + col] = acc[i][j][r] + bias[col];
            }
}

// ---------------------------------------------------------------------------
// Gt[z][d2][d1] = SCALE^2 * sum_m q_y[m,d2]*k_y[m,d1]  (q_x carries
// SCALE*log2e -> prod logits get SCALE^3*log2e total).
// 4 waves split the M=512 reduction (128 each), LDS tree-reduce.
// ---------------------------------------------------------------------------
__global__ __launch_bounds__(256) void gt_k(const ushort_t* __restrict__ qyT,
                                            const ushort_t* __restrict__ kyT,
                                            ushort_t* __restrict__ Gt)
{
    const int z = blockIdx.x;
    const int tid = threadIdx.x, w = tid >> 6, lane = tid & 63;
    const int quad = lane >> 4, l15 = lane & 15;
    const ushort_t* A  = qyT + (long)z * 64 * MMM;
    const ushort_t* Bm = kyT + (long)z * 64 * MMM;
    __shared__ float red[4][4096];
    f4 acc[4][4] = {};
    for (int kk = 0; kk < 4; ++kk) {
        const int ks = w * 4 + kk;
        s8v af[4], bfr[4];
#pragma unroll
        for (int i = 0; i < 4; ++i) {
            af[i]  = *(const s8v*)(A  + (long)(16 * i + l15) * MMM + ks * 32 + quad * 8);
            bfr[i] = *(const s8v*)(Bm + (long)(16 * i + l15) * MMM + ks * 32 + quad * 8);
        }
#pragma unroll
        for (int i = 0; i < 4; ++i)
#pragma unroll
            for (int j = 0; j < 4; ++j)
                acc[i][j] = __builtin_amdgcn_mfma_f32_16x16x32_bf16(af[i], bfr[j], acc[i][j], 0, 0, 0);
    }
#pragma unroll
    for (int i = 0; i < 4; ++i)
#pragma unroll
        for (int j = 0; j < 4; ++j)
            *(f4*)&red[w][(i * 4 + j) * 256 + lane * 4] = acc[i][j];
    __syncthreads();
    const float s2 = SCALE * SCALE;
#pragma unroll
    for (int j = 0; j < 4; ++j) {
        f4 s = *(const f4*)&red[0][(w * 4 + j) * 256 + lane * 4];
#pragma unroll
        for (int ww = 1; ww < 4; ++ww)
            s += *(const f4*)&red[ww][(w * 4 + j) * 256 + lane * 4];
#pragma unroll
        for (int r = 0; r < 4; ++r) {
            int d2 = 16 * w + quad * 4 + r, d1 = 16 * j + l15;
            Gt[(long)z * 4096 + d2 * 64 + d1] = f2bf(s2 * s[r]);
        }
    }
}

// ---------------------------------------------------------------------------
// Fused 3-stream flash, R17: one 8-wave block per qtile PAIR (p, 31-p).
// Grid 16x16 = 256 blocks = exactly 1/CU (LDS 84KB). Group A = waves 0-3
// (qtile p), group B = waves 4-7 (qtile 31-p). Shared K/V staging ring
// (3 slots, counted vmcnt, 1 barrier/round):
//   rounds 0..7   : cross tiles    -> each group its own cross stream (T1)
//   rounds 8..8+p : causal prefix  -> each group dual-stream own qtile (T2)
//   (A writes qA out at u==p, reloads Q for qB)
//   remaining     : causal suffix of qB, STREAM-SPLIT: A=self, B=prod (T1)
// Block rounds = (39-2p)T1 + (p+1)T2 ~= 41*T1 constant (T2~=2T1) -> every
// CU runs 8 busy waves for the same duration; zero global partials (A's
// self-partial combined into B through retired K-LDS, lane-aligned).
// Fetch drops ~34%: pair shares all cross + prefix tiles.
// ---------------------------------------------------------------------------
__device__ __forceinline__ void stage_k8(const ushort_t* src, long rstride, int s0,
                                         ushort_t* Kl, int w2, int lane) {
    int f = w2 * 1024 + lane * 16;
    int row = f >> 7;
    int krow = ((row & 15) << 2) | (row >> 4);   // k-interleave permutation
    int blk = ((f & 127) >> 4) ^ (row & 7);
    gload16(src + (long)(s0 + krow) * rstride + blk * 8, &Kl[(w2 * 1024) >> 1]);
}
__device__ __forceinline__ void stage_v8(const ushort_t* src, long rstride, int s0,
                                         ushort_t* Vl, int w2, int lane) {
    int f = w2 * 1024 + lane * 16;
    int row = f >> 7;
    int blk = ((f & 127) >> 4) ^ (row & 7);
    gload16(src + (long)row * rstride + s0 + blk * 8, &Vl[(w2 * 1024) >> 1]);
}
__device__ __forceinline__ void qk8(f4 Sc[4], const s8v qf[2], const ushort_t* Kl,
                                    int quad, int l15) {
    __builtin_amdgcn_s_setprio(1);
#pragma unroll
    for (int ks = 0; ks < 2; ++ks)
#pragma unroll
        for (int c = 0; c < 4; ++c) {
            int row = 16 * c + l15;
            s8v bb = *(const s8v*)&Kl[row * 64 + (((ks * 4 + quad) ^ (row & 7)) * 8)];
            Sc[c] = __builtin_amdgcn_mfma_f32_16x16x32_bf16(qf[ks], bb, Sc[c], 0, 0, 0);
        }
    __builtin_amdgcn_s_setprio(0);
}
__device__ __forceinline__ void qk8_dual(f4 Ss[4], f4 Sp[4], const s8v qa[2], const s8v qb[2],
                                         const ushort_t* Kl, int quad, int l15) {
    __builtin_amdgcn_s_setprio(1);
#pragma unroll
    for (int ks = 0; ks < 2; ++ks)
#pragma unroll
        for (int c = 0; c < 4; ++c) {
            int row = 16 * c + l15;
            s8v bb = *(const s8v*)&Kl[row * 64 + (((ks * 4 + quad) ^ (row & 7)) * 8)];
            Ss[c] = __builtin_amdgcn_mfma_f32_16x16x32_bf16(qa[ks], bb, Ss[c], 0, 0, 0);
            Sp[c] = __builtin_amdgcn_mfma_f32_16x16x32_bf16(qb[ks], bb, Sp[c], 0, 0, 0);
        }
    __builtin_amdgcn_s_setprio(0);
}
// fixed-max softmax: p = 2^v (logits pre-scaled by log2e); lane-local l;
// P written as packed b64 (k-cols 4*l15..4*l15+3 consecutive after interleave)
__device__ __forceinline__ void smax0(const f4 Sc[4], float l_i[4], ushort_t* PlW,
                                      int diag, int trow0, int s0, int quad, int l15) {
#pragma unroll
    for (int r = 0; r < 4; ++r) {
        const int trow = trow0 + quad * 4 + r;
        u16x4 o;
#pragma unroll
        for (int c = 0; c < 4; ++c) {
            float v = Sc[c][r];
            if (diag && (s0 + 4 * l15 + c) > trow) v = -3e38f;
            float p = exp2_raw(v);
            l_i[r] += p;
            o[c] = f2bf(p);
        }
        *(u16x4*)&PlW[(quad * 4 + r) * 72 + 4 * l15] = o;
    }
}
__device__ __forceinline__ void pv8(f4 Oc[4], const ushort_t* PlW, const ushort_t* Vl,
                                    int quad, int l15) {
    __builtin_amdgcn_s_setprio(1);
#pragma unroll
    for (int ks = 0; ks < 2; ++ks) {
        s8v a = *(const s8v*)&PlW[l15 * 72 + ks * 32 + quad * 8];
#pragma unroll
        for (int c = 0; c < 4; ++c) {
            int row = 16 * c + l15;
            s8v bb = *(const s8v*)&Vl[row * 64 + (((ks * 4 + quad) ^ (row & 7)) * 8)];
            Oc[c] = __builtin_amdgcn_mfma_f32_16x16x32_bf16(a, bb, Oc[c], 0, 0, 0);
        }
    }
    __builtin_amdgcn_s_setprio(0);
}
__device__ __forceinline__ void pv8_dual(f4 Os[4], f4 Op[4], const ushort_t* Ps,
                                         const ushort_t* Pp, const ushort_t* Vl,
                                         int quad, int l15) {
    __builtin_amdgcn_s_setprio(1);
#pragma unroll
    for (int ks = 0; ks < 2; ++ks) {
        s8v as = *(const s8v*)&Ps[l15 * 72 + ks * 32 + quad * 8];
        s8v ap = *(const s8v*)&Pp[l15 * 72 + ks * 32 + quad * 8];
#pragma unroll
        for (int c = 0; c < 4; ++c) {
            int row = 16 * c + l15;
            s8v bb = *(const s8v*)&Vl[row * 64 + (((ks * 4 + quad) ^ (row & 7)) * 8)];
            Os[c] = __builtin_amdgcn_mfma_f32_16x16x32_bf16(as, bb, Os[c], 0, 0, 0);
            Op[c] = __builtin_amdgcn_mfma_f32_16x16x32_bf16(ap, bb, Op[c], 0, 0, 0);
        }
    }
    __builtin_amdgcn_s_setprio(0);
}
__device__ __forceinline__ void reduce16(float (&a)[4], float (&b)[4], float (&c)[4]) {
#pragma unroll
    for (int r = 0; r < 4; ++r)
#pragma unroll
        for (int mb = 1; mb < 16; mb <<= 1) {
            a[r] += __shfl_xor(a[r], mb, 64);
            b[r] += __shfl_xor(b[r], mb, 64);
            c[r] += __shfl_xor(c[r], mb, 64);
        }
}

__global__ __launch_bounds__(512, 2) void flash_fused(
    const ushort_t* __restrict__ qkvx, const ushort_t* __restrict__ qkvy,
    const ushort_t* __restrict__ Gt, const ushort_t* __restrict__ vxT,
    const ushort_t* __restrict__ vyT,
    ushort_t* __restrict__ cval, ushort_t* __restrict__ sval)
{
    const int z = blockIdx.y, b = z >> 3, h = z & 7;
    const int p = blockIdx.x;                 // pair id: qtiles p and 31-p
    const ushort_t* qx = qkvx + (long)b * (TT * 1536) + h * 64;   // pre-scaled SCALE*log2e
    const ushort_t* kx = qx + 512;
    const ushort_t* ky = qkvy + (long)b * (MMM * 1536) + 512 + h * 64;
    const ushort_t* Gz = Gt + (long)z * 4096;
    const ushort_t* vx = vxT + (long)z * (64 * TT);
    const ushort_t* vy = vyT + (long)z * (64 * MMM);

    const int tid = threadIdx.x, w2 = tid >> 6, lane = tid & 63;
    const int g = w2 >> 2, w = w2 & 3;        // group (0=A,1=B), wave-in-group
    const int quad = lane >> 4, l15 = lane & 15;
    const int qB = 31 - p;
    const int qg = g ? qB : p;                // own qtile

    __shared__ __align__(16) ushort_t Kl[3][64 * 64];
    __shared__ __align__(16) ushort_t Vl[3][64 * 64];
    __shared__ __align__(16) ushort_t Pl[2][8 * 16 * 72];
    ushort_t* PlWs = &Pl[0][w2 * 1152];
    ushort_t* PlWp = &Pl[1][w2 * 1152];

    // prefetch cross tiles 0,1 (always exist; 8 cross tiles total)
    stage_k8(ky, 1536, 0, Kl[0], w2, lane);
    stage_v8(vy, MMM, 0, Vl[0], w2, lane);
    stage_k8(ky, 1536, 64, Kl[1], w2, lane);
    stage_v8(vy, MMM, 64, Vl[1], w2, lane);

    // Q frags for own qtile + q~ = qx_scaled @ Gt^T (LDS roundtrip, wave-private)
    s8v qfx[2], qft[2];
    {
        const int qrow = qg * 64 + 16 * w + l15;
        qfx[0] = *(const s8v*)(qx + (long)qrow * 1536 + quad * 8);
        qfx[1] = *(const s8v*)(qx + (long)qrow * 1536 + 32 + quad * 8);
        f4 qa[4] = {};
#pragma unroll
        for (int ks = 0; ks < 2; ++ks)
#pragma unroll
            for (int j = 0; j < 4; ++j) {
                s8v bb = *(const s8v*)(Gz + (4 * l15 + j) * 64 + ks * 32 + quad * 8);
                qa[j] = __builtin_amdgcn_mfma_f32_16x16x32_bf16(qfx[ks], bb, qa[j], 0, 0, 0);
            }
#pragma unroll
        for (int r = 0; r < 4; ++r) {
            u16x4 o;
#pragma unroll
            for (int j = 0; j < 4; ++j) o[j] = f2bf(qa[j][r]);
            *(u16x4*)&PlWs[(quad * 4 + r) * 72 + 4 * l15] = o;
        }
        qft[0] = *(const s8v*)&PlWs[l15 * 72 + quad * 8];
        qft[1] = *(const s8v*)&PlWs[l15 * 72 + 32 + quad * 8];
    }
    asm volatile("s_waitcnt vmcnt(0)" ::: "memory");
    asm volatile("s_barrier" ::: "memory");

    f4 Occ[4] = {}, Ocs[4] = {}, Ocp[4] = {};
    float lc[4] = {}, ls[4] = {}, lp[4] = {};

    const long obase = (long)b * (TT * CC) + h * 64;
    const int n = 40 - p;                     // 8 cross + (31-p+1) causal tiles
    int cur = 0;
    for (int ti = 0; ti < n; ++ti) {
        if (ti > 0) {
            // own tile-ti loads done (tile ti+1's 2 loads may stay in flight)
            if (ti + 1 < n) asm volatile("s_waitcnt vmcnt(2)" ::: "memory");
            else            asm volatile("s_waitcnt vmcnt(0)" ::: "memory");
            asm volatile("s_barrier" ::: "memory");
        }
        if (ti + 2 < n) {
            int s = cur + 2; if (s >= 3) s -= 3;
            const int tn = ti + 2;
            if (tn < 8) {
                stage_k8(ky, 1536, tn * 64, Kl[s], w2, lane);
                stage_v8(vy, MMM, tn * 64, Vl[s], w2, lane);
            } else {
                const int u = tn - 8;
                stage_k8(kx, 1536, u * 64, Kl[s], w2, lane);
                stage_v8(vx, TT, u * 64, Vl[s], w2, lane);
            }
        }
        if (ti < 8) {
            // cross stream, own qtile
            f4 Sc[4] = {};
            qk8(Sc, qfx, Kl[cur], quad, l15);
            smax0(Sc, lc, PlWs, 0, 0, 0, quad, l15);
            pv8(Occ, PlWs, Vl[cur], quad, l15);
        } else {
            const int u = ti - 8;
            if (u <= p) {
                // causal prefix: dual-stream own qtile (A diag at u==p)
                const int diag = (u == qg);
                f4 Ss[4] = {}, Sp[4] = {};
                qk8_dual(Ss, Sp, qfx, qft, Kl[cur], quad, l15);
                smax0(Ss, ls, PlWs, diag, qg * 64 + 16 * w, u * 64, quad, l15);
                smax0(Sp, lp, PlWp, diag, qg * 64 + 16 * w, u * 64, quad, l15);
                pv8_dual(Ocs, Ocp, PlWs, PlWp, Vl[cur], quad, l15);
            } else {
                // suffix of qB, stream-split: A=self, B=prod
                const int diag = (u == qB);
                if (g == 0) {
                    f4 Ss[4] = {};
                    qk8(Ss, qfx, Kl[cur], quad, l15);     // qfx = qB rows here
                    smax0(Ss, ls, PlWs, diag, qB * 64 + 16 * w, u * 64, quad, l15);
                    pv8(Ocs, PlWs, Vl[cur], quad, l15);
                } else {
                    f4 Sp[4] = {};
                    qk8(Sp, qft, Kl[cur], quad, l15);
                    smax0(Sp, lp, PlWp, diag, qB * 64 + 16 * w, u * 64, quad, l15);
                    pv8(Ocp, PlWp, Vl[cur], quad, l15);
                }
            }
            // A finishes qA at its diagonal: write out, reset, switch to qB
            if (u == p && g == 0) {
                reduce16(lc, ls, lp);
#pragma unroll
                for (int r = 0; r < 4; ++r) {
                    int row = p * 64 + 16 * w + quad * 4 + r;
                    float ic = 1.f / lc[r], ip = 1.f / lp[r], isv = 1.f / ls[r];
#pragma unroll
                    for (int c = 0; c < 4; ++c) {
                        long idx = obase + (long)row * CC + 16 * c + l15;
                        cval[idx] = f2bf(Occ[c][r] * ic + Ocp[c][r] * ip);
                        sval[idx] = f2bf(Ocs[c][r] * isv);
                    }
                }
#pragma unroll
                for (int c = 0; c < 4; ++c) Ocs[c] = f4{};
#pragma unroll
                for (int r = 0; r < 4; ++r) ls[r] = 0.f;
                const int qrow2 = qB * 64 + 16 * w + l15;
                qfx[0] = *(const s8v*)(qx + (long)qrow2 * 1536 + quad * 8);
                qfx[1] = *(const s8v*)(qx + (long)qrow2 * 1536 + 32 + quad * 8);
            }
        }
        if (++cur == 3) cur = 0;
    }

    // combine A's qB self-partial into B (lane-aligned: A wave w <-> B wave w)
    __syncthreads();
    float* comb = (float*)&Kl[0][0];          // 20KB of retired K ring
    const int cbase = (w * 64 + lane) * 20;
    if (g == 0) {
#pragma unroll
        for (int c = 0; c < 4; ++c) *(f4*)&comb[cbase + 4 * c] = Ocs[c];
#pragma unroll
        for (int r = 0; r < 4; ++r) comb[cbase + 16 + r] = ls[r];
    }
    __syncthreads();
    if (g == 1) {
#pragma unroll
        for (int c = 0; c < 4; ++c) Ocs[c] += *(const f4*)&comb[cbase + 4 * c];
#pragma unroll
        for (int r = 0; r < 4; ++r) ls[r] += comb[cbase + 16 + r];
        reduce16(lc, ls, lp);
#pragma unroll
        for (int r = 0; r < 4; ++r) {
            int row = qB * 64 + 16 * w + quad * 4 + r;
            float ic = 1.f / lc[r], ip = 1.f / lp[r], isv = 1.f / ls[r];
#pragma unroll
            for (int c = 0; c < 4; ++c) {
                long idx = obase + (long)row * CC + 16 * c + l15;
                cval[idx] = f2bf(Occ[c][r] * ic + Ocp[c][r] * ip);
                sval[idx] = f2bf(Ocs[c][r] * isv);
            }
        }
    }
}

// ---------------------------------------------------------------------------
// Fused gate. 64x64 tile (grid 8x64 = 512 blocks), 16 flattened k-steps
// (2 passes x 8), 3-slot ring + counted vmcnt.
// ---------------------------------------------------------------------------
__global__ __launch_bounds__(256) void gate_gemm(
    const ushort_t* __restrict__ sval, const ushort_t* __restrict__ cvalb,
    const ushort_t* __restrict__ WgsT, const ushort_t* __restrict__ WgcT,
    const float* __restrict__ bgs, const float* __restrict__ bgc,
    ushort_t* __restrict__ tmpb)
{
    const int r0 = blockIdx.y * 64, c0 = blockIdx.x * 64;
    const int tid = threadIdx.x, w = tid >> 6, lane = tid & 63;
    const int quad = lane >> 4, l15 = lane & 15;
    const int rowBase = (w >> 1) * 32, colBase = (w & 1) * 32;

    __shared__ __align__(16) ushort_t Al[3][64 * 64];
    __shared__ __align__(16) ushort_t Bl[3][64 * 64];

    const ushort_t* Ap[2] = { sval + (long)r0 * 512, cvalb + (long)r0 * 512 };
    const ushort_t* Bp[2] = { WgsT + (long)c0 * 512, WgcT + (long)c0 * 512 };

    f4 acc1[2][2] = {}, acc2[2][2] = {};

    stage_rows64(Ap[0], 0, Al[0], w, lane);
    stage_rows64(Bp[0], 0, Bl[0], w, lane);
    stage_rows64(Ap[0], 64, Al[1], w, lane);
    stage_rows64(Bp[0], 64, Bl[1], w, lane);

    int cur = 0;
    for (int st = 0; st < 16; ++st) {
        if (st + 1 < 16) asm volatile("s_waitcnt vmcnt(4)" ::: "memory");
        else             asm volatile("s_waitcnt vmcnt(0)" ::: "memory");
        asm volatile("s_barrier" ::: "memory");
        if (st + 2 < 16) {
            int s = cur + 2; if (s >= 3) s -= 3;
            const int nx = st + 2, p = nx >> 3;
            stage_rows64(Ap[p], (nx & 7) * 64, Al[s], w, lane);
            stage_rows64(Bp[p], (nx & 7) * 64, Bl[s], w, lane);
        }
#pragma unroll
        for (int ks = 0; ks < 2; ++ks) {
            s8v af[2], bfr[2];
#pragma unroll
            for (int i = 0; i < 2; ++i) {
                int row = rowBase + 16 * i + l15;
                af[i] = *(const s8v*)&Al[cur][row * 64 + (((ks * 4 + quad) ^ (row & 7)) * 8)];
                int col = colBase + 16 * i + l15;
                bfr[i] = *(const s8v*)&Bl[cur][col * 64 + (((ks * 4 + quad) ^ (col & 7)) * 8)];
            }
            if (st < 8) {
#pragma unroll
                for (int i = 0; i < 2; ++i)
#pragma unroll
                    for (int j = 0; j < 2; ++j)
                        acc1[i][j] = __builtin_amdgcn_mfma_f32_16x16x32_bf16(af[i], bfr[j], acc1[i][j], 0, 0, 0);
            } else {
#pragma unroll
                for (int i = 0; i < 2; ++i)
#pragma unroll
                    for (int j = 0; j < 2; ++j)
                        acc2[i][j] = __builtin_amdgcn_mfma_f32_16x16x32_bf16(af[i], bfr[j], acc2[i][j], 0, 0, 0);
            }
        }
        if (++cur == 3) cur = 0;
    }

#pragma unroll
    for (int i = 0; i < 2; ++i)
#pragma unroll
        for (int j = 0; j < 2; ++j)
#pragma unroll
            for (int r = 0; r < 4; ++r) {
                int row = r0 + rowBase + 16 * i + quad * 4 + r;
                int col = c0 + colBase + 16 * j + l15;
                long idx = (long)row * 512 + col;
                float g1 = 1.f / (1.f + __expf(-(acc1[i][j][r] + bgs[col])));
                float g2 = 1.f / (1.f + __expf(-(acc2[i][j][r] + bgc[col])));
                tmpb[idx] = f2bf(g1 * bf2f(cvalb[idx]) + g2 * bf2f(sval[idx]));
            }
}

extern "C" void kernel_launch(void* const* d_in, const int* in_sizes, int n_in,
                              void* d_out, int out_size, void* d_ws, size_t ws_size,
                              hipStream_t stream) {
    const float* x      = (const float*)d_in[0];
    const float* y      = (const float*)d_in[1];
    // d_in[2] = attn_x_mask (deterministic tril) -> causal branch
    const float* Wqkv_x = (const float*)d_in[3];
    const float* bqkv_x = (const float*)d_in[4];
    const float* Wqkv_y = (const float*)d_in[5];
    const float* bqkv_y = (const float*)d_in[6];
    const float* Wgs    = (const float*)d_in[7];
    const float* bgs    = (const float*)d_in[8];
    const float* Wgc    = (const float*)d_in[9];
    const float* bgc    = (const float*)d_in[10];
    const float* Wp     = (const float*)d_in[11];
    const float* bp     = (const float*)d_in[12];
    float* out = (float*)d_out;

    // ---- workspace (bf16 shorts), ~46 MB ----
    ushort_t* u = (ushort_t*)d_ws;
    long o = 0;
    ushort_t* xb    = u + o; o += (long)BB * TT * CC;
    ushort_t* yb    = u + o; o += (long)BB * MMM * CC;
    ushort_t* WqxT  = u + o; o += 1536L * 512;
    ushort_t* WqyT  = u + o; o += 1536L * 512;
    ushort_t* WgsT  = u + o; o += 512L * 512;
    ushort_t* WgcT  = u + o; o += 512L * 512;
    ushort_t* WpT   = u + o; o += 512L * 512;
    ushort_t* qkvx  = u + o; o += (long)BB * TT * 1536;
    ushort_t* qkvy  = u + o; o += (long)BB * MMM * 1536;
    ushort_t* vxT   = u + o; o += (long)BB * HH * DD * TT;
    ushort_t* vyT   = u + o; o += (long)BB * HH * DD * MMM;
    ushort_t* kyT   = u + o; o += (long)BB * HH * DD * MMM;
    ushort_t* qyT   = u + o; o += (long)BB * HH * DD * MMM;
    ushort_t* Gt    = u + o; o += 16L * 64 * 64;
    ushort_t* cvalb = u + o; o += (long)BB * TT * CC;
    ushort_t* sval  = u + o; o += (long)BB * TT * CC;
    ushort_t* tmpb  = u + o; o += (long)BB * TT * CC;

    dim3 blk(256);

    // 1) prep: conversions + weight transposes
    prep_k<<<dim3(4864), blk, 0, stream>>>(x, y, Wqkv_x, Wqkv_y, Wgs, Wgc, Wp,
                                           xb, yb, WqxT, WqyT, WgsT, WgcT, WpT);

    // 2) combined qkv projections (q_x pre-scaled by SCALE*log2e)
    qkv_k<<<dim3(12, 40), blk, 0, stream>>>(xb, yb, WqxT, WqyT, bqkv_x, bqkv_y, qkvx, qkvy);

    // 3) fused slice transposes (vectorized)
    vT_fused<<<dim3(56, 16), blk, 0, stream>>>(qkvx, qkvy, vxT, vyT, kyT, qyT);

    // 4) Gt = SCALE^2 * Q_y^T K_y (4-wave split-M + LDS reduce)
    gt_k<<<dim3(16), blk, 0, stream>>>(qyT, kyT, Gt);

    // 5) fused 3-stream flash — 8-wave pair blocks, constant rounds per CU
    flash_fused<<<dim3(16, 16), dim3(512), 0, stream>>>(qkvx, qkvy, Gt, vxT, vyT,
                                                        cvalb, sval);

    // 6) fused gates + combine (64x64 tile, 512 blocks, 3-ring pipeline)
    gate_gemm<<<dim3(8, 64), blk, 0, stream>>>(sval, cvalb, WgsT, WgcT, bgs, bgc, tmpb);

    // 7) out = tmpb @ Wp + bp (fp32, 64x64 tile, 512 blocks, 3-ring pipeline)
    proj_k<<<dim3(8, 64), blk, 0, stream>>>(tmpb, WpT, out, bp);
}

// Round 6
// 205.129 us; speedup vs baseline: 1.0643x; 1.0520x over previous
//
#include <hip/hip_runtime.h>
#include <hip/hip_bf16.h>

typedef unsigned short ushort_t;
typedef __attribute__((ext_vector_type(8))) short s8v;   // 8 bf16 = 4 VGPR (MFMA A/B frag)
typedef __attribute__((ext_vector_type(4))) float f4;    // 4 fp32 acc (MFMA C/D frag)
typedef __attribute__((ext_vector_type(4))) unsigned short u16x4;

// Problem constants: B=2, T=2048, M=512, C=512, H=8, D=64
#define BB 2
#define TT 2048
#define MMM 512
#define CC 512
#define HH 8
#define DD 64
#define SCALE 0.125f
// SCALE * log2(e): folded into q_x so softmax uses bare v_exp_f32 (2^x)
#define SCALE_L2E 0.18033688011112042f

__device__ __forceinline__ ushort_t f2bf(float v) {
    __hip_bfloat16 h = __float2bfloat16(v);
    return *reinterpret_cast<ushort_t*>(&h);
}
__device__ __forceinline__ float bf2f(ushort_t u) {
    __hip_bfloat16 h;
    *reinterpret_cast<ushort_t*>(&h) = u;
    return __bfloat162float(h);
}
// bare 2^x (v_exp_f32). Inputs pre-scaled by log2(e).
__device__ __forceinline__ float exp2_raw(float v) {
    float p;
    asm("v_exp_f32 %0, %1" : "=v"(p) : "v"(v));
    return p;
}

// async global->LDS, 16B per lane. LDS dst = wave-uniform base + lane*16.
__device__ __forceinline__ void gload16(const void* g, void* l) {
    __builtin_amdgcn_global_load_lds((const __attribute__((address_space(1))) void*)g,
                                     (__attribute__((address_space(3))) void*)l, 16, 0, 0);
}

// ---------------------------------------------------------------------------
// prep_k: x/y fp32->bf16 (float4-vectorized) + 5 weight transposes.
// ---------------------------------------------------------------------------
__device__ __forceinline__ void transp32(const float* W, ushort_t* WT, int K, int N,
                                         int bx, int by, int tid) {
    const int k0 = by * 32, n0 = bx * 32;
    __shared__ float t[32][33];
    for (int i = tid; i < 1024; i += 256) {
        int r = i >> 5, c = i & 31;
        t[r][c] = W[(long)(k0 + r) * N + n0 + c];
    }
    __syncthreads();
    for (int i = tid; i < 1024; i += 256) {
        int r = i >> 5, c = i & 31;
        WT[(long)(n0 + r) * K + k0 + c] = f2bf(t[c][r]);
    }
}
__device__ __forceinline__ void cvt4(const float* s, ushort_t* d, long blk, int tid) {
    long i = (blk * 256 + tid) * 4;
    float4 v = *(const float4*)(s + i);
    u16x4 o;
    o[0] = f2bf(v.x); o[1] = f2bf(v.y); o[2] = f2bf(v.z); o[3] = f2bf(v.w);
    *(u16x4*)(d + i) = o;
}

__global__ __launch_bounds__(256) void prep_k(
    const float* __restrict__ x, const float* __restrict__ y,
    const float* __restrict__ Wqx, const float* __restrict__ Wqy,
    const float* __restrict__ Wgs, const float* __restrict__ Wgc,
    const float* __restrict__ Wp,
    ushort_t* __restrict__ xb, ushort_t* __restrict__ yb,
    ushort_t* __restrict__ WqxT, ushort_t* __restrict__ WqyT,
    ushort_t* __restrict__ WgsT, ushort_t* __restrict__ WgcT,
    ushort_t* __restrict__ WpT)
{
    const int bid = blockIdx.x, tid = threadIdx.x;
    if (bid < 2048)      cvt4(x, xb, bid, tid);
    else if (bid < 2560) cvt4(y, yb, bid - 2048, tid);
    else if (bid < 3328) { int l = bid - 2560; transp32(Wqx, WqxT, 512, 1536, l % 48, l / 48, tid); }
    else if (bid < 4096) { int l = bid - 3328; transp32(Wqy, WqyT, 512, 1536, l % 48, l / 48, tid); }
    else if (bid < 4352) { int l = bid - 4096; transp32(Wgs, WgsT, 512, 512, l % 16, l / 16, tid); }
    else if (bid < 4608) { int l = bid - 4352; transp32(Wgc, WgcT, 512, 512, l % 16, l / 16, tid); }
    else                 { int l = bid - 4608; transp32(Wp, WpT, 512, 512, l % 16, l / 16, tid); }
}

// ---------------------------------------------------------------------------
// fused slice transposes: vxT | vyT | kyT | qyT  -> dst[z][d][S]
// vectorized (16B/lane both global sides), swizzled LDS tile.
// ---------------------------------------------------------------------------
__global__ __launch_bounds__(256) void vT_fused(
    const ushort_t* __restrict__ qkvx, const ushort_t* __restrict__ qkvy,
    ushort_t* __restrict__ vxT, ushort_t* __restrict__ vyT,
    ushort_t* __restrict__ kyT, ushort_t* __restrict__ qyT)
{
    const int bx = blockIdx.x, z = blockIdx.y, b = z >> 3, h = z & 7;
    const ushort_t* src; ushort_t* dst; int S, s0; long sB, dZ;
    if (bx < 32)      { src = qkvx + 1024; dst = vxT; S = TT;  sB = (long)TT * 1536;  dZ = (long)64 * TT;  s0 = bx * 64; }
    else if (bx < 40) { src = qkvy + 1024; dst = vyT; S = MMM; sB = (long)MMM * 1536; dZ = (long)64 * MMM; s0 = (bx - 32) * 64; }
    else if (bx < 48) { src = qkvy + 512;  dst = kyT; S = MMM; sB = (long)MMM * 1536; dZ = (long)64 * MMM; s0 = (bx - 40) * 64; }
    else              { src = qkvy;        dst = qyT; S = MMM; sB = (long)MMM * 1536; dZ = (long)64 * MMM; s0 = (bx - 48) * 64; }
    const ushort_t* sp = src + (long)b * sB + (long)h * 64;
    ushort_t* dp = dst + (long)z * dZ;
    __shared__ __align__(16) ushort_t t[64][80];
    const int tid = threadIdx.x;
#pragma unroll
    for (int p = 0; p < 2; ++p) {
        int id = tid + p * 256;
        int r = id >> 3, cc = (id & 7) * 8;
        int cs = cc ^ ((r >> 3) * 8);
        *(s8v*)&t[r][cs] = *(const s8v*)&sp[(long)(s0 + r) * 1536 + cc];
    }
    __syncthreads();
#pragma unroll
    for (int p = 0; p < 2; ++p) {
        int id = tid + p * 256;
        int d = id >> 3, cc = (id & 7) * 8;
        s8v o;
#pragma unroll
        for (int k = 0; k < 8; ++k) {
            int r = cc + k;
            o[k] = (short)t[r][d ^ ((r >> 3) * 8)];
        }
        *(s8v*)&dp[(long)d * S + s0 + cc] = o;
    }
}

// ---------------------------------------------------------------------------
// staging helpers (XOR-swizzled LDS layout, 16B/lane global_load_lds)
// ---------------------------------------------------------------------------
__device__ __forceinline__ void stage_rows128(const ushort_t* src, long k0,
                                              ushort_t* dstL, int w, int lane) {
#pragma unroll
    for (int n = 0; n < 4; ++n) {
        int f = w * 4096 + n * 1024 + lane * 16;
        int row = f >> 7;
        int blk_g = ((f & 127) >> 4) ^ (row & 7);
        gload16(src + (long)row * 512 + k0 + blk_g * 8, dstL + ((w * 4096 + n * 1024) >> 1));
    }
}
__device__ __forceinline__ void stage_rows64(const ushort_t* src, long k0,
                                             ushort_t* dstL, int w, int lane) {
#pragma unroll
    for (int n = 0; n < 2; ++n) {
        int f = w * 2048 + n * 1024 + lane * 16;
        int row = f >> 7;
        int blk_g = ((f & 127) >> 4) ^ (row & 7);
        gload16(src + (long)row * 512 + k0 + blk_g * 8, dstL + ((w * 2048 + n * 1024) >> 1));
    }
}

// ---------------------------------------------------------------------------
// Combined QKV NT GEMM: by<32 -> x branch (q cols pre-scaled by SCALE*log2e),
// by in [32,40) -> y branch. 128x128 tile, BK=64, double-buffered.
// ---------------------------------------------------------------------------
__global__ __launch_bounds__(256) void qkv_k(
    const ushort_t* __restrict__ xb, const ushort_t* __restrict__ yb,
    const ushort_t* __restrict__ WqxT, const ushort_t* __restrict__ WqyT,
    const float* __restrict__ bqx, const float* __restrict__ bqy,
    ushort_t* __restrict__ qkvx, ushort_t* __restrict__ qkvy)
{
    const int by = blockIdx.y;
    const ushort_t* A; const ushort_t* Bm; const float* bias; ushort_t* O;
    int r0, qcols;
    if (by < 32) { A = xb; Bm = WqxT; bias = bqx; O = qkvx; r0 = by * 128; qcols = 512; }
    else         { A = yb; Bm = WqyT; bias = bqy; O = qkvy; r0 = (by - 32) * 128; qcols = 0; }
    const int c0 = blockIdx.x * 128;
    const int tid = threadIdx.x, w = tid >> 6, lane = tid & 63;
    const int quad = lane >> 4, l15 = lane & 15;
    const int rowBase = (w >> 1) * 64, colBase = (w & 1) * 64;

    __shared__ __align__(16) ushort_t Al[2][128 * 64];
    __shared__ __align__(16) ushort_t Bl[2][128 * 64];

    const ushort_t* Ab = A + (long)r0 * 512;
    const ushort_t* Bb = Bm + (long)c0 * 512;

    f4 acc[4][4] = {};

    stage_rows128(Ab, 0, Al[0], w, lane);
    stage_rows128(Bb, 0, Bl[0], w, lane);
    __syncthreads();

    for (int kk = 0; kk < 8; ++kk) {
        const int cur = kk & 1;
        if (kk < 7) {
            stage_rows128(Ab, (kk + 1) * 64, Al[cur ^ 1], w, lane);
            stage_rows128(Bb, (kk + 1) * 64, Bl[cur ^ 1], w, lane);
        }
#pragma unroll
        for (int ks = 0; ks < 2; ++ks) {
            s8v af[4], bfr[4];
#pragma unroll
            for (int i = 0; i < 4; ++i) {
                int row = rowBase + 16 * i + l15;
                af[i] = *(const s8v*)&Al[cur][row * 64 + (((ks * 4 + quad) ^ (row & 7)) * 8)];
                int col = colBase + 16 * i + l15;
                bfr[i] = *(const s8v*)&Bl[cur][col * 64 + (((ks * 4 + quad) ^ (col & 7)) * 8)];
            }
#pragma unroll
            for (int i = 0; i < 4; ++i)
#pragma unroll
                for (int j = 0; j < 4; ++j)
                    acc[i][j] = __builtin_amdgcn_mfma_f32_16x16x32_bf16(af[i], bfr[j], acc[i][j], 0, 0, 0);
        }
        __syncthreads();
    }

#pragma unroll
    for (int i = 0; i < 4; ++i)
#pragma unroll
        for (int j = 0; j < 4; ++j)
#pragma unroll
            for (int r = 0; r < 4; ++r) {
                int row = r0 + rowBase + 16 * i + quad * 4 + r;
                int col = c0 + colBase + 16 * j + l15;
                float v = acc[i][j][r] + bias[col];
                if (col < qcols) v *= SCALE_L2E;   // fold SCALE*log2e into q_x
                O[(long)row * 1536 + col] = f2bf(v);
            }
}

// ---------------------------------------------------------------------------
// Proj NT GEMM. 64x64 tile (grid 8x64 = 512 blocks -> 2 blocks/CU),
// 3-slot ring + counted vmcnt single-barrier pipeline.
// ---------------------------------------------------------------------------
__global__ __launch_bounds__(256) void proj_k(
    const ushort_t* __restrict__ A, const ushort_t* __restrict__ Bm,
    float* __restrict__ O, const float* __restrict__ bias)
{
    const int r0 = blockIdx.y * 64, c0 = blockIdx.x * 64;
    const int tid = threadIdx.x, w = tid >> 6, lane = tid & 63;
    const int quad = lane >> 4, l15 = lane & 15;
    const int rowBase = (w >> 1) * 32, colBase = (w & 1) * 32;

    __shared__ __align__(16) ushort_t Al[3][64 * 64];
    __shared__ __align__(16) ushort_t Bl[3][64 * 64];

    const ushort_t* Ab = A + (long)r0 * 512;
    const ushort_t* Bb = Bm + (long)c0 * 512;

    f4 acc[2][2] = {};

    stage_rows64(Ab, 0, Al[0], w, lane);
    stage_rows64(Bb, 0, Bl[0], w, lane);
    stage_rows64(Ab, 64, Al[1], w, lane);
    stage_rows64(Bb, 64, Bl[1], w, lane);

    int cur = 0;
    for (int kk = 0; kk < 8; ++kk) {
        if (kk + 1 < 8) asm volatile("s_waitcnt vmcnt(4)" ::: "memory");
        else            asm volatile("s_waitcnt vmcnt(0)" ::: "memory");
        asm volatile("s_barrier" ::: "memory");
        if (kk + 2 < 8) {
            int s = cur + 2; if (s >= 3) s -= 3;
            stage_rows64(Ab, (kk + 2) * 64, Al[s], w, lane);
            stage_rows64(Bb, (kk + 2) * 64, Bl[s], w, lane);
        }
#pragma unroll
        for (int ks = 0; ks < 2; ++ks) {
            s8v af[2], bfr[2];
#pragma unroll
            for (int i = 0; i < 2; ++i) {
                int row = rowBase + 16 * i + l15;
                af[i] = *(const s8v*)&Al[cur][row * 64 + (((ks * 4 + quad) ^ (row & 7)) * 8)];
                int col = colBase + 16 * i + l15;
                bfr[i] = *(const s8v*)&Bl[cur][col * 64 + (((ks * 4 + quad) ^ (col & 7)) * 8)];
            }
#pragma unroll
            for (int i = 0; i < 2; ++i)
#pragma unroll
                for (int j = 0; j < 2; ++j)
                    acc[i][j] = __builtin_amdgcn_mfma_f32_16x16x32_bf16(af[i], bfr[j], acc[i][j], 0, 0, 0);
        }
        if (++cur == 3) cur = 0;
    }

#pragma unroll
    for (int i = 0; i < 2; ++i)
#pragma unroll
        for (int j = 0; j < 2; ++j)
#pragma unroll
            for (int r = 0; r < 4; ++r) {
                int row = r0 + rowBase + 16 * i + quad * 4 + r;
                int col = c0 + colBase + 16 * j + l15;
                O[(long)row * 512 + col] = acc[i][j][r] + bias[col];
            }
}

// ---------------------------------------------------------------------------
// Gt[z][d2][d1] = SCALE^2 * sum_m q_y[m,d2]*k_y[m,d1]  (q_x carries
// SCALE*log2e -> prod logits get SCALE^3*log2e total).
// 4 waves split the M=512 reduction (128 each), LDS tree-reduce.
// ---------------------------------------------------------------------------
__global__ __launch_bounds__(256) void gt_k(const ushort_t* __restrict__ qyT,
                                            const ushort_t* __restrict__ kyT,
                                            ushort_t* __restrict__ Gt)
{
    const int z = blockIdx.x;
    const int tid = threadIdx.x, w = tid >> 6, lane = tid & 63;
    const int quad = lane >> 4, l15 = lane & 15;
    const ushort_t* A  = qyT + (long)z * 64 * MMM;
    const ushort_t* Bm = kyT + (long)z * 64 * MMM;
    __shared__ float red[4][4096];
    f4 acc[4][4] = {};
    for (int kk = 0; kk < 4; ++kk) {
        const int ks = w * 4 + kk;
        s8v af[4], bfr[4];
#pragma unroll
        for (int i = 0; i < 4; ++i) {
            af[i]  = *(const s8v*)(A  + (long)(16 * i + l15) * MMM + ks * 32 + quad * 8);
            bfr[i] = *(const s8v*)(Bm + (long)(16 * i + l15) * MMM + ks * 32 + quad * 8);
        }
#pragma unroll
        for (int i = 0; i < 4; ++i)
#pragma unroll
            for (int j = 0; j < 4; ++j)
                acc[i][j] = __builtin_amdgcn_mfma_f32_16x16x32_bf16(af[i], bfr[j], acc[i][j], 0, 0, 0);
    }
#pragma unroll
    for (int i = 0; i < 4; ++i)
#pragma unroll
        for (int j = 0; j < 4; ++j)
            *(f4*)&red[w][(i * 4 + j) * 256 + lane * 4] = acc[i][j];
    __syncthreads();
    const float s2 = SCALE * SCALE;
#pragma unroll
    for (int j = 0; j < 4; ++j) {
        f4 s = *(const f4*)&red[0][(w * 4 + j) * 256 + lane * 4];
#pragma unroll
        for (int ww = 1; ww < 4; ++ww)
            s += *(const f4*)&red[ww][(w * 4 + j) * 256 + lane * 4];
#pragma unroll
        for (int r = 0; r < 4; ++r) {
            int d2 = 16 * w + quad * 4 + r, d1 = 16 * j + l15;
            Gt[(long)z * 4096 + d2 * 64 + d1] = f2bf(s2 * s[r]);
        }
    }
}

// ---------------------------------------------------------------------------
// Fused 3-stream flash.
// R18 changes vs R15 (best measured structure, 60-61us):
//  * PV DEFERRED BY ONE TILE: round ti = qk(ti) -> pv(ti-1) -> smax(ti).
//    pv(ti-1)'s MFMAs are independent of smax(ti)'s VALU chain -> MFMA and
//    VALU pipes overlap WITHIN a wave (was: qk->smax->pv fully serial; the
//    counter signature MfmaUtil 13% + VALUBusy 28% motivated this).
//  * No P double-buffer: P is wave-private; pv(ti-1)'s ds_reads precede
//    smax(ti)'s ds_writes in program order (aliasing preserved; pv's MFMA
//    lgkm waits force read-return before the writes issue).
//  * V ring 3->4 slots (V[ti-1] must survive stage(ti+2): distance 3 mod 4).
//    LDS = 24K(Kx3)+32K(Vx4)+18.4K(P) = 75.8KB -> still 2 blocks/CU.
//  * R5's pair-block experiment reverted: occupancy rose 13->18% with dur
//    WORSE -> starvation is not the limiter, the per-wave chain is.
// ---------------------------------------------------------------------------
__device__ __forceinline__ void stage_k64(const ushort_t* src, long rstride, int s0,
                                          ushort_t* Kl, int w, int lane) {
#pragma unroll
    for (int n = 0; n < 2; ++n) {
        int f = w * 2048 + n * 1024 + lane * 16;
        int row = f >> 7;
        int krow = ((row & 15) << 2) | (row >> 4);   // k-interleave permutation
        int blk = ((f & 127) >> 4) ^ (row & 7);
        gload16(src + (long)(s0 + krow) * rstride + blk * 8, &Kl[(w * 2048 + n * 1024) >> 1]);
    }
}
__device__ __forceinline__ void stage_v64(const ushort_t* src, long rstride, int s0,
                                          ushort_t* Vl, int w, int lane) {
#pragma unroll
    for (int n = 0; n < 2; ++n) {
        int f = w * 2048 + n * 1024 + lane * 16;
        int row = f >> 7;
        int blk = ((f & 127) >> 4) ^ (row & 7);
        gload16(src + (long)row * rstride + s0 + blk * 8, &Vl[(w * 2048 + n * 1024) >> 1]);
    }
}
__device__ __forceinline__ void qk8(f4 Sc[4], const s8v qf[2], const ushort_t* Kl,
                                    int quad, int l15) {
    __builtin_amdgcn_s_setprio(1);
#pragma unroll
    for (int ks = 0; ks < 2; ++ks)
#pragma unroll
        for (int c = 0; c < 4; ++c) {
            int row = 16 * c + l15;
            s8v bb = *(const s8v*)&Kl[row * 64 + (((ks * 4 + quad) ^ (row & 7)) * 8)];
            Sc[c] = __builtin_amdgcn_mfma_f32_16x16x32_bf16(qf[ks], bb, Sc[c], 0, 0, 0);
        }
    __builtin_amdgcn_s_setprio(0);
}
__device__ __forceinline__ void qk8_dual(f4 Ss[4], f4 Sp[4], const s8v qa[2], const s8v qb[2],
                                         const ushort_t* Kl, int quad, int l15) {
    __builtin_amdgcn_s_setprio(1);
#pragma unroll
    for (int ks = 0; ks < 2; ++ks)
#pragma unroll
        for (int c = 0; c < 4; ++c) {
            int row = 16 * c + l15;
            s8v bb = *(const s8v*)&Kl[row * 64 + (((ks * 4 + quad) ^ (row & 7)) * 8)];
            Ss[c] = __builtin_amdgcn_mfma_f32_16x16x32_bf16(qa[ks], bb, Ss[c], 0, 0, 0);
            Sp[c] = __builtin_amdgcn_mfma_f32_16x16x32_bf16(qb[ks], bb, Sp[c], 0, 0, 0);
        }
    __builtin_amdgcn_s_setprio(0);
}
// fixed-max softmax: p = 2^v (logits pre-scaled by log2e); lane-local l;
// P written as packed b64 (k-cols 4*l15..4*l15+3 consecutive after interleave)
__device__ __forceinline__ void smax0(const f4 Sc[4], float l_i[4], ushort_t* PlW,
                                      int diag, int trow0, int s0, int quad, int l15) {
#pragma unroll
    for (int r = 0; r < 4; ++r) {
        const int trow = trow0 + quad * 4 + r;
        u16x4 o;
#pragma unroll
        for (int c = 0; c < 4; ++c) {
            float v = Sc[c][r];
            if (diag && (s0 + 4 * l15 + c) > trow) v = -3e38f;
            float p = exp2_raw(v);
            l_i[r] += p;
            o[c] = f2bf(p);
        }
        *(u16x4*)&PlW[(quad * 4 + r) * 72 + 4 * l15] = o;
    }
}
__device__ __forceinline__ void pv8(f4 Oc[4], const ushort_t* PlW, const ushort_t* Vl,
                                    int quad, int l15) {
    __builtin_amdgcn_s_setprio(1);
#pragma unroll
    for (int ks = 0; ks < 2; ++ks) {
        s8v a = *(const s8v*)&PlW[l15 * 72 + ks * 32 + quad * 8];
#pragma unroll
        for (int c = 0; c < 4; ++c) {
            int row = 16 * c + l15;
            s8v bb = *(const s8v*)&Vl[row * 64 + (((ks * 4 + quad) ^ (row & 7)) * 8)];
            Oc[c] = __builtin_amdgcn_mfma_f32_16x16x32_bf16(a, bb, Oc[c], 0, 0, 0);
        }
    }
    __builtin_amdgcn_s_setprio(0);
}
__device__ __forceinline__ void pv8_dual(f4 Os[4], f4 Op[4], const ushort_t* Ps,
                                         const ushort_t* Pp, const ushort_t* Vl,
                                         int quad, int l15) {
    __builtin_amdgcn_s_setprio(1);
#pragma unroll
    for (int ks = 0; ks < 2; ++ks) {
        s8v as = *(const s8v*)&Ps[l15 * 72 + ks * 32 + quad * 8];
        s8v ap = *(const s8v*)&Pp[l15 * 72 + ks * 32 + quad * 8];
#pragma unroll
        for (int c = 0; c < 4; ++c) {
            int row = 16 * c + l15;
            s8v bb = *(const s8v*)&Vl[row * 64 + (((ks * 4 + quad) ^ (row & 7)) * 8)];
            Os[c] = __builtin_amdgcn_mfma_f32_16x16x32_bf16(as, bb, Os[c], 0, 0, 0);
            Op[c] = __builtin_amdgcn_mfma_f32_16x16x32_bf16(ap, bb, Op[c], 0, 0, 0);
        }
    }
    __builtin_amdgcn_s_setprio(0);
}

__global__ __launch_bounds__(256, 2) void flash_fused(
    const ushort_t* __restrict__ qkvx, const ushort_t* __restrict__ qkvy,
    const ushort_t* __restrict__ Gt, const ushort_t* __restrict__ vxT,
    const ushort_t* __restrict__ vyT,
    ushort_t* __restrict__ cval, ushort_t* __restrict__ sval)
{
    const int z = blockIdx.y, b = z >> 3, h = z & 7;
    const ushort_t* qx = qkvx + (long)b * (TT * 1536) + h * 64;   // pre-scaled SCALE*log2e
    const ushort_t* kx = qx + 512;
    const ushort_t* ky = qkvy + (long)b * (MMM * 1536) + 512 + h * 64;
    const ushort_t* Gz = Gt + (long)z * 4096;
    const ushort_t* vx = vxT + (long)z * (64 * TT);
    const ushort_t* vy = vyT + (long)z * (64 * MMM);

    // load-balance: z<8 long-first, z>=8 short-first (R2's best-measured pairing)
    const int xw = (z & 8) ? (int)blockIdx.x : (int)(gridDim.x - 1 - blockIdx.x);
    const int t0 = xw * 64;
    const int tid = threadIdx.x, w = tid >> 6, lane = tid & 63;
    const int quad = lane >> 4, l15 = lane & 15;

    __shared__ __align__(16) ushort_t Kl[3][64 * 64];
    __shared__ __align__(16) ushort_t Vl[4][64 * 64];
    __shared__ __align__(16) ushort_t Pl[2][4 * 16 * 72];   // [stream][wave P]
    ushort_t* PlWs = &Pl[0][w * 1152];
    ushort_t* PlWp = &Pl[1][w * 1152];

    // prefetch tiles 0,1 (both cross; nTiles >= 9 always)
    stage_k64(ky, 1536, 0, Kl[0], w, lane);
    stage_v64(vy, MMM, 0, Vl[0], w, lane);
    stage_k64(ky, 1536, 64, Kl[1], w, lane);
    stage_v64(vy, MMM, 64, Vl[1], w, lane);

    // Q frags + q~ = qx_scaled @ Gt^T (permuted Gt rows -> packed P writes).
    // The q/Gz loads' data-waits drain vmcnt -> tiles 0,1 resident per wave.
    const int qrow = t0 + 16 * w + l15;
    s8v qfx[2], qft[2];
    qfx[0] = *(const s8v*)(qx + (long)qrow * 1536 + quad * 8);
    qfx[1] = *(const s8v*)(qx + (long)qrow * 1536 + 32 + quad * 8);
    {
        f4 qa[4] = {};
#pragma unroll
        for (int ks = 0; ks < 2; ++ks)
#pragma unroll
            for (int j = 0; j < 4; ++j) {
                s8v bb = *(const s8v*)(Gz + (4 * l15 + j) * 64 + ks * 32 + quad * 8);
                qa[j] = __builtin_amdgcn_mfma_f32_16x16x32_bf16(qfx[ks], bb, qa[j], 0, 0, 0);
            }
#pragma unroll
        for (int r = 0; r < 4; ++r) {
            u16x4 o;
#pragma unroll
            for (int j = 0; j < 4; ++j) o[j] = f2bf(qa[j][r]);
            *(u16x4*)&PlWs[(quad * 4 + r) * 72 + 4 * l15] = o;
        }
        qft[0] = *(const s8v*)&PlWs[l15 * 72 + quad * 8];
        qft[1] = *(const s8v*)&PlWs[l15 * 72 + 32 + quad * 8];
    }

    f4 Occ[4] = {}, Ocs[4] = {}, Ocp[4] = {};
    float lc[4] = {}, ls[4] = {}, lp[4] = {};

    const int nT1 = MMM / 64;                 // 8 cross tiles
    const int nTiles = nT1 + t0 / 64 + 1;

    asm volatile("s_waitcnt vmcnt(0)" ::: "memory");
    asm volatile("s_barrier" ::: "memory");

    int cur = 0;                              // K ring index = ti % 3
    for (int ti = 0; ti < nTiles; ++ti) {
        if (ti > 0) {
            // own tile-ti loads done (tile ti+1's 4 loads may stay in flight)
            if (ti + 1 < nTiles) asm volatile("s_waitcnt vmcnt(4)" ::: "memory");
            else                 asm volatile("s_waitcnt vmcnt(0)" ::: "memory");
            asm volatile("s_barrier" ::: "memory");
        }
        if (ti + 2 < nTiles) {
            int s3 = cur + 2; if (s3 >= 3) s3 -= 3;
            const int tn = ti + 2, s4 = tn & 3;
            if (tn < nT1) {
                stage_k64(ky, 1536, tn * 64, Kl[s3], w, lane);
                stage_v64(vy, MMM, tn * 64, Vl[s4], w, lane);
            } else {
                const int s0n = (tn - nT1) * 64;
                stage_k64(kx, 1536, s0n, Kl[s3], w, lane);
                stage_v64(vx, TT, s0n, Vl[s4], w, lane);
            }
        }
        if (ti < nT1) {
            // ---- cross: qk(ti) -> deferred pv(ti-1) -> smax(ti) ----
            f4 Sc[4] = {};
            qk8(Sc, qfx, Kl[cur], quad, l15);
            if (ti > 0) pv8(Occ, PlWs, Vl[(ti - 1) & 3], quad, l15);   // prev is cross
            smax0(Sc, lc, PlWs, 0, 0, 0, quad, l15);
        } else {
            // ---- causal: qk_dual(ti) -> deferred pv(ti-1) -> 2x smax(ti) ----
            const int s0 = (ti - nT1) * 64;
            const int diag = (s0 == t0);
            f4 Ss[4] = {}, Sp[4] = {};
            qk8_dual(Ss, Sp, qfx, qft, Kl[cur], quad, l15);
            if (ti == nT1) pv8(Occ, PlWs, Vl[(ti - 1) & 3], quad, l15);          // prev cross
            else           pv8_dual(Ocs, Ocp, PlWs, PlWp, Vl[(ti - 1) & 3], quad, l15);
            smax0(Ss, ls, PlWs, diag, t0 + 16 * w, s0, quad, l15);
            smax0(Sp, lp, PlWp, diag, t0 + 16 * w, s0, quad, l15);
        }
        if (++cur == 3) cur = 0;
    }
    // final deferred pv: tile nTiles-1 is always causal (nTiles-1 >= nT1)
    pv8_dual(Ocs, Ocp, PlWs, PlWp, Vl[(nTiles - 1) & 3], quad, l15);

    // reduce l over the 16 lanes of each quad-group (cols of the row)
#pragma unroll
    for (int r = 0; r < 4; ++r)
#pragma unroll
        for (int mb = 1; mb < 16; mb <<= 1) {
            lc[r] += __shfl_xor(lc[r], mb, 64);
            ls[r] += __shfl_xor(ls[r], mb, 64);
            lp[r] += __shfl_xor(lp[r], mb, 64);
        }

    const long ob = (long)b * (TT * CC) + h * 64;
#pragma unroll
    for (int r = 0; r < 4; ++r) {
        int row = t0 + 16 * w + quad * 4 + r;
        float ic = 1.f / lc[r], ip = 1.f / lp[r], isv = 1.f / ls[r];
#pragma unroll
        for (int c = 0; c < 4; ++c) {
            long idx = ob + (long)row * CC + 16 * c + l15;
            cval[idx] = f2bf(Occ[c][r] * ic + Ocp[c][r] * ip);
            sval[idx] = f2bf(Ocs[c][r] * isv);
        }
    }
}

// ---------------------------------------------------------------------------
// Fused gate. 64x64 tile (grid 8x64 = 512 blocks), 16 flattened k-steps
// (2 passes x 8), 3-slot ring + counted vmcnt.
// ---------------------------------------------------------------------------
__global__ __launch_bounds__(256) void gate_gemm(
    const ushort_t* __restrict__ sval, const ushort_t* __restrict__ cvalb,
    const ushort_t* __restrict__ WgsT, const ushort_t* __restrict__ WgcT,
    const float* __restrict__ bgs, const float* __restrict__ bgc,
    ushort_t* __restrict__ tmpb)
{
    const int r0 = blockIdx.y * 64, c0 = blockIdx.x * 64;
    const int tid = threadIdx.x, w = tid >> 6, lane = tid & 63;
    const int quad = lane >> 4, l15 = lane & 15;
    const int rowBase = (w >> 1) * 32, colBase = (w & 1) * 32;

    __shared__ __align__(16) ushort_t Al[3][64 * 64];
    __shared__ __align__(16) ushort_t Bl[3][64 * 64];

    const ushort_t* Ap[2] = { sval + (long)r0 * 512, cvalb + (long)r0 * 512 };
    const ushort_t* Bp[2] = { WgsT + (long)c0 * 512, WgcT + (long)c0 * 512 };

    f4 acc1[2][2] = {}, acc2[2][2] = {};

    stage_rows64(Ap[0], 0, Al[0], w, lane);
    stage_rows64(Bp[0], 0, Bl[0], w, lane);
    stage_rows64(Ap[0], 64, Al[1], w, lane);
    stage_rows64(Bp[0], 64, Bl[1], w, lane);

    int cur = 0;
    for (int st = 0; st < 16; ++st) {
        if (st + 1 < 16) asm volatile("s_waitcnt vmcnt(4)" ::: "memory");
        else             asm volatile("s_waitcnt vmcnt(0)" ::: "memory");
        asm volatile("s_barrier" ::: "memory");
        if (st + 2 < 16) {
            int s = cur + 2; if (s >= 3) s -= 3;
            const int nx = st + 2, p = nx >> 3;
            stage_rows64(Ap[p], (nx & 7) * 64, Al[s], w, lane);
            stage_rows64(Bp[p], (nx & 7) * 64, Bl[s], w, lane);
        }
#pragma unroll
        for (int ks = 0; ks < 2; ++ks) {
            s8v af[2], bfr[2];
#pragma unroll
            for (int i = 0; i < 2; ++i) {
                int row = rowBase + 16 * i + l15;
                af[i] = *(const s8v*)&Al[cur][row * 64 + (((ks * 4 + quad) ^ (row & 7)) * 8)];
                int col = colBase + 16 * i + l15;
                bfr[i] = *(const s8v*)&Bl[cur][col * 64 + (((ks * 4 + quad) ^ (col & 7)) * 8)];
            }
            if (st < 8) {
#pragma unroll
                for (int i = 0; i < 2; ++i)
#pragma unroll
                    for (int j = 0; j < 2; ++j)
                        acc1[i][j] = __builtin_amdgcn_mfma_f32_16x16x32_bf16(af[i], bfr[j], acc1[i][j], 0, 0, 0);
            } else {
#pragma unroll
                for (int i = 0; i < 2; ++i)
#pragma unroll
                    for (int j = 0; j < 2; ++j)
                        acc2[i][j] = __builtin_amdgcn_mfma_f32_16x16x32_bf16(af[i], bfr[j], acc2[i][j], 0, 0, 0);
            }
        }
        if (++cur == 3) cur = 0;
    }

#pragma unroll
    for (int i = 0; i < 2; ++i)
#pragma unroll
        for (int j = 0; j < 2; ++j)
#pragma unroll
            for (int r = 0; r < 4; ++r) {
                int row = r0 + rowBase + 16 * i + quad * 4 + r;
                int col = c0 + colBase + 16 * j + l15;
                long idx = (long)row * 512 + col;
                float g1 = 1.f / (1.f + __expf(-(acc1[i][j][r] + bgs[col])));
                float g2 = 1.f / (1.f + __expf(-(acc2[i][j][r] + bgc[col])));
                tmpb[idx] = f2bf(g1 * bf2f(cvalb[idx]) + g2 * bf2f(sval[idx]));
            }
}

extern "C" void kernel_launch(void* const* d_in, const int* in_sizes, int n_in,
                              void* d_out, int out_size, void* d_ws, size_t ws_size,
                              hipStream_t stream) {
    const float* x      = (const float*)d_in[0];
    const float* y      = (const float*)d_in[1];
    // d_in[2] = attn_x_mask (deterministic tril) -> causal branch
    const float* Wqkv_x = (const float*)d_in[3];
    const float* bqkv_x = (const float*)d_in[4];
    const float* Wqkv_y = (const float*)d_in[5];
    const float* bqkv_y = (const float*)d_in[6];
    const float* Wgs    = (const float*)d_in[7];
    const float* bgs    = (const float*)d_in[8];
    const float* Wgc    = (const float*)d_in[9];
    const float* bgc    = (const float*)d_in[10];
    const float* Wp     = (const float*)d_in[11];
    const float* bp     = (const float*)d_in[12];
    float* out = (float*)d_out;

    // ---- workspace (bf16 shorts), ~46 MB ----
    ushort_t* u = (ushort_t*)d_ws;
    long o = 0;
    ushort_t* xb    = u + o; o += (long)BB * TT * CC;
    ushort_t* yb    = u + o; o += (long)BB * MMM * CC;
    ushort_t* WqxT  = u + o; o += 1536L * 512;
    ushort_t* WqyT  = u + o; o += 1536L * 512;
    ushort_t* WgsT  = u + o; o += 512L * 512;
    ushort_t* WgcT  = u + o; o += 512L * 512;
    ushort_t* WpT   = u + o; o += 512L * 512;
    ushort_t* qkvx  = u + o; o += (long)BB * TT * 1536;
    ushort_t* qkvy  = u + o; o += (long)BB * MMM * 1536;
    ushort_t* vxT   = u + o; o += (long)BB * HH * DD * TT;
    ushort_t* vyT   = u + o; o += (long)BB * HH * DD * MMM;
    ushort_t* kyT   = u + o; o += (long)BB * HH * DD * MMM;
    ushort_t* qyT   = u + o; o += (long)BB * HH * DD * MMM;
    ushort_t* Gt    = u + o; o += 16L * 64 * 64;
    ushort_t* cvalb = u + o; o += (long)BB * TT * CC;
    ushort_t* sval  = u + o; o += (long)BB * TT * CC;
    ushort_t* tmpb  = u + o; o += (long)BB * TT * CC;

    dim3 blk(256);

    // 1) prep: conversions + weight transposes
    prep_k<<<dim3(4864), blk, 0, stream>>>(x, y, Wqkv_x, Wqkv_y, Wgs, Wgc, Wp,
                                           xb, yb, WqxT, WqyT, WgsT, WgcT, WpT);

    // 2) combined qkv projections (q_x pre-scaled by SCALE*log2e)
    qkv_k<<<dim3(12, 40), blk, 0, stream>>>(xb, yb, WqxT, WqyT, bqkv_x, bqkv_y, qkvx, qkvy);

    // 3) fused slice transposes (vectorized)
    vT_fused<<<dim3(56, 16), blk, 0, stream>>>(qkvx, qkvy, vxT, vyT, kyT, qyT);

    // 4) Gt = SCALE^2 * Q_y^T K_y (4-wave split-M + LDS reduce)
    gt_k<<<dim3(16), blk, 0, stream>>>(qyT, kyT, Gt);

    // 5) fused 3-stream flash (deferred-PV pipeline, MFMA/VALU overlap)
    flash_fused<<<dim3(32, 16), blk, 0, stream>>>(qkvx, qkvy, Gt, vxT, vyT, cvalb, sval);

    // 6) fused gates + combine (64x64 tile, 512 blocks, 3-ring pipeline)
    gate_gemm<<<dim3(8, 64), blk, 0, stream>>>(sval, cvalb, WgsT, WgcT, bgs, bgc, tmpb);

    // 7) out = tmpb @ Wp + bp (fp32, 64x64 tile, 512 blocks, 3-ring pipeline)
    proj_k<<<dim3(8, 64), blk, 0, stream>>>(tmpb, WpT, out, bp);
}